// Round 1
// baseline (1412.064 us; speedup 1.0000x reference)
//
#include <hip/hip_runtime.h>

#define SCAN_CHUNK 1024

// ---------------- CSR build ----------------

__global__ void count_edges(const int* __restrict__ dst, int* __restrict__ cnt, int E) {
    int e = blockIdx.x * 256 + threadIdx.x;
    if (e < E) atomicAdd(&cnt[dst[e]], 1);
}

__global__ void scan_partial(const int* __restrict__ cnt, int* __restrict__ partials, int n) {
    __shared__ int red[256];
    int b = blockIdx.x, t = threadIdx.x;
    int base = b * SCAN_CHUNK;
    int s = 0;
    for (int j = t; j < SCAN_CHUNK; j += 256) {
        int idx = base + j;
        if (idx < n) s += cnt[idx];
    }
    red[t] = s;
    __syncthreads();
    for (int off = 128; off > 0; off >>= 1) {
        if (t < off) red[t] += red[t + off];
        __syncthreads();
    }
    if (t == 0) partials[b] = red[0];
}

// single block of 128 threads; nchunk <= 128
__global__ void scan_partials_excl(int* partials, int nchunk, int* row_start, int n, int E) {
    __shared__ int s[128];
    int t = threadIdx.x;
    int orig = (t < nchunk) ? partials[t] : 0;
    s[t] = orig;
    __syncthreads();
    for (int off = 1; off < 128; off <<= 1) {
        int add = (t >= off) ? s[t - off] : 0;
        __syncthreads();
        s[t] += add;
        __syncthreads();
    }
    if (t < nchunk) partials[t] = s[t] - orig;   // exclusive
    if (t == 0) row_start[n] = E;
}

__global__ void scan_final(const int* __restrict__ cnt, const int* __restrict__ partials,
                           int* __restrict__ row_start, int* __restrict__ cursor, int n) {
    __shared__ int sh[256];
    int b = blockIdx.x, t = threadIdx.x;
    int base = b * SCAN_CHUNK + t * 4;
    int v[4];
    int tot = 0;
#pragma unroll
    for (int j = 0; j < 4; j++) {
        int idx = base + j;
        v[j] = (idx < n) ? cnt[idx] : 0;
        tot += v[j];
    }
    sh[t] = tot;
    __syncthreads();
    for (int off = 1; off < 256; off <<= 1) {
        int add = (t >= off) ? sh[t - off] : 0;
        __syncthreads();
        sh[t] += add;
        __syncthreads();
    }
    int run = partials[b] + sh[t] - tot;   // block-exclusive + thread-exclusive
#pragma unroll
    for (int j = 0; j < 4; j++) {
        int idx = base + j;
        if (idx < n) { row_start[idx] = run; cursor[idx] = run; }
        run += v[j];
    }
}

__global__ void scatter_edges(const int* __restrict__ src, const int* __restrict__ dst,
                              int* __restrict__ cursor, int* __restrict__ sorted_src, int E) {
    int e = blockIdx.x * 256 + threadIdx.x;
    if (e < E) {
        int p = atomicAdd(&cursor[dst[e]], 1);
        sorted_src[p] = src[e];
    }
}

// ---------------- aggregation (segment mean via CSR gather) ----------------

template <int F>
__global__ void aggregate_mean(const float* __restrict__ hin, float* __restrict__ out,
                               const int* __restrict__ srcs, const int* __restrict__ rs, int n) {
    int tid = blockIdx.x * 256 + threadIdx.x;
    if (tid >= n * F) return;
    int i = tid / F;
    int f = tid & (F - 1);
    int lo = rs[i], hi = rs[i + 1];
    float s = 0.f;
    for (int e = lo; e < hi; ++e) s += hin[(size_t)srcs[e] * F + f];
    out[tid] = s * (1.0f / (float)max(hi - lo, 1));
}

// ---------------- fused linear: out = relu(A@Wl + H@Wr + b), out width 128 ----------------

template <int K>
__launch_bounds__(256)
__global__ void fused_linear2(const float* __restrict__ A, const float* __restrict__ Hm,
                              const float* __restrict__ Wl, const float* __restrict__ Wr,
                              const float* __restrict__ bias, float* __restrict__ out, int n) {
    __shared__ float4 sA[32][K / 4];
    __shared__ float4 sH[32][K / 4];
    int b = blockIdx.x, t = threadIdx.x;
    int base = b * 32;
    int rows = min(32, n - base);
    const float4* A4 = (const float4*)(A + (size_t)base * K);
    const float4* H4 = (const float4*)(Hm + (size_t)base * K);
    int nv = rows * (K / 4);
    for (int j = t; j < nv; j += 256) {
        ((float4*)sA)[j] = A4[j];
        ((float4*)sH)[j] = H4[j];
    }
    __syncthreads();
    int o = t & 127, r = t >> 7;
    float bo = bias[o];
    float acc[16];
#pragma unroll
    for (int m = 0; m < 16; m++) acc[m] = bo;
    for (int kk = 0; kk < K / 4; ++kk) {
        float wl[4], wr[4];
#pragma unroll
        for (int q = 0; q < 4; q++) {
            wl[q] = Wl[(4 * kk + q) * 128 + o];
            wr[q] = Wr[(4 * kk + q) * 128 + o];
        }
#pragma unroll
        for (int m = 0; m < 16; m++) {
            int node = r * 16 + m;
            float4 av = sA[node][kk];
            float4 hv = sH[node][kk];
            acc[m] += av.x * wl[0] + av.y * wl[1] + av.z * wl[2] + av.w * wl[3]
                    + hv.x * wr[0] + hv.y * wr[1] + hv.z * wr[2] + hv.w * wr[3];
        }
    }
#pragma unroll
    for (int m = 0; m < 16; m++) {
        int node = r * 16 + m;
        if (node < rows) out[(size_t)(base + node) * 128 + o] = fmaxf(acc[m], 0.f);
    }
}

// ---------------- single linear: out = relu(A@W + b), K=128, out width 128 ----------------

__launch_bounds__(256)
__global__ void single_linear(const float* __restrict__ A, const float* __restrict__ W,
                              const float* __restrict__ bias, float* __restrict__ out, int n) {
    __shared__ float4 sA[32][32];
    int b = blockIdx.x, t = threadIdx.x;
    int base = b * 32;
    int rows = min(32, n - base);
    const float4* A4 = (const float4*)(A + (size_t)base * 128);
    int nv = rows * 32;
    for (int j = t; j < nv; j += 256) ((float4*)sA)[j] = A4[j];
    __syncthreads();
    int o = t & 127, r = t >> 7;
    float bo = bias[o];
    float acc[16];
#pragma unroll
    for (int m = 0; m < 16; m++) acc[m] = bo;
    for (int kk = 0; kk < 32; ++kk) {
        float w[4];
#pragma unroll
        for (int q = 0; q < 4; q++) w[q] = W[(4 * kk + q) * 128 + o];
#pragma unroll
        for (int m = 0; m < 16; m++) {
            float4 av = sA[r * 16 + m][kk];
            acc[m] += av.x * w[0] + av.y * w[1] + av.z * w[2] + av.w * w[3];
        }
    }
#pragma unroll
    for (int m = 0; m < 16; m++) {
        int node = r * 16 + m;
        if (node < rows) out[(size_t)(base + node) * 128 + o] = fmaxf(acc[m], 0.f);
    }
}

// ---------------- head ----------------

// d1 = h . Wfc[:,0] + bfc[0]; d3 = h . Wfc[:,2] + bfc[2] ; one wave per node
__global__ void head_a(const float* __restrict__ h, const float* __restrict__ Wfc,
                       const float* __restrict__ bfc, float* __restrict__ fin, int n) {
    int wid = (blockIdx.x * 256 + threadIdx.x) >> 6;
    int lane = threadIdx.x & 63;
    if (wid >= n) return;
    float2 hv = ((const float2*)h)[(size_t)wid * 64 + lane];
    int k0 = 2 * lane, k1 = 2 * lane + 1;
    float p1 = hv.x * Wfc[k0 * 3 + 0] + hv.y * Wfc[k1 * 3 + 0];
    float p3 = hv.x * Wfc[k0 * 3 + 2] + hv.y * Wfc[k1 * 3 + 2];
    for (int m = 1; m < 64; m <<= 1) {
        p1 += __shfl_xor(p1, m, 64);
        p3 += __shfl_xor(p3, m, 64);
    }
    if (lane == 0) {
        fin[(size_t)wid * 3 + 0] = p1 + bfc[0];
        fin[(size_t)wid * 3 + 2] = p3 + bfc[2];
    }
}

// a1 = relu(d1*Wa1[0,:] + d3*Wa1[1,:] + ba1)
__global__ void head_b(const float* __restrict__ fin, const float* __restrict__ Wa1,
                       const float* __restrict__ ba1, float* __restrict__ a1, int n) {
    int tid = blockIdx.x * 256 + threadIdx.x;
    if (tid >= n * 128) return;
    int i = tid >> 7, j = tid & 127;
    float d1 = fin[(size_t)i * 3 + 0];
    float d3 = fin[(size_t)i * 3 + 2];
    a1[tid] = fmaxf(d1 * Wa1[j] + d3 * Wa1[128 + j] + ba1[j], 0.f);
}

// fin[:,1] = a2 . Wao + bao ; one wave per node
__global__ void head_d(const float* __restrict__ a2, const float* __restrict__ Wao,
                       const float* __restrict__ bao, float* __restrict__ fin, int n) {
    int wid = (blockIdx.x * 256 + threadIdx.x) >> 6;
    int lane = threadIdx.x & 63;
    if (wid >= n) return;
    float2 av = ((const float2*)a2)[(size_t)wid * 64 + lane];
    float2 wv = ((const float2*)Wao)[lane];
    float p = av.x * wv.x + av.y * wv.y;
    for (int m = 1; m < 64; m <<= 1) p += __shfl_xor(p, m, 64);
    if (lane == 0) fin[(size_t)wid * 3 + 1] = p + bao[0];
}

// per-graph mean pool; batch is sorted; one block per graph
__global__ void pool_kernel(const float* __restrict__ fin, const int* __restrict__ batch,
                            float* __restrict__ out, int n) {
    int g = blockIdx.x, t = threadIdx.x;
    int lo = 0, hi = n;
    while (lo < hi) { int mid = (lo + hi) >> 1; if (batch[mid] < g) lo = mid + 1; else hi = mid; }
    int start = lo;
    lo = 0; hi = n;
    while (lo < hi) { int mid = (lo + hi) >> 1; if (batch[mid] < g + 1) lo = mid + 1; else hi = mid; }
    int end = lo;
    float s0 = 0.f, s1 = 0.f, s2 = 0.f;
    for (int i = start + t; i < end; i += 256) {
        s0 += fin[(size_t)i * 3 + 0];
        s1 += fin[(size_t)i * 3 + 1];
        s2 += fin[(size_t)i * 3 + 2];
    }
    __shared__ float r0[256], r1[256], r2[256];
    r0[t] = s0; r1[t] = s1; r2[t] = s2;
    __syncthreads();
    for (int off = 128; off > 0; off >>= 1) {
        if (t < off) { r0[t] += r0[t + off]; r1[t] += r1[t + off]; r2[t] += r2[t + off]; }
        __syncthreads();
    }
    if (t == 0) {
        float c = (float)max(end - start, 1);
        out[g * 3 + 0] = r0[0] / c;
        out[g * 3 + 1] = r1[0] / c;
        out[g * 3 + 2] = r2[0] / c;
    }
}

// ---------------- launch ----------------

extern "C" void kernel_launch(void* const* d_in, const int* in_sizes, int n_in,
                              void* d_out, int out_size, void* d_ws, size_t ws_size,
                              hipStream_t stream) {
    const float* x    = (const float*)d_in[0];
    const int*   ei   = (const int*)d_in[1];
    const int*   batch= (const int*)d_in[2];
    const float* Wl0  = (const float*)d_in[3];
    const float* bl0  = (const float*)d_in[4];
    const float* Wr0  = (const float*)d_in[5];
    const float* Wl1  = (const float*)d_in[6];
    const float* bl1  = (const float*)d_in[7];
    const float* Wr1  = (const float*)d_in[8];
    const float* Wl2  = (const float*)d_in[9];
    const float* bl2  = (const float*)d_in[10];
    const float* Wr2  = (const float*)d_in[11];
    const float* Wfc  = (const float*)d_in[12];
    const float* bfc  = (const float*)d_in[13];
    const float* Wa1  = (const float*)d_in[14];
    const float* ba1  = (const float*)d_in[15];
    const float* Wa2  = (const float*)d_in[16];
    const float* ba2  = (const float*)d_in[17];
    const float* Wao  = (const float*)d_in[18];
    const float* bao  = (const float*)d_in[19];

    const int N = in_sizes[0] / 32;
    const int E = in_sizes[1] / 2;
    const int G = out_size / 3;
    const int* src = ei;
    const int* dst = ei + E;
    float* out = (float*)d_out;

    // workspace carve-up (256B-aligned)
    char* p = (char*)d_ws;
    auto carve = [&](size_t bytes) {
        void* r = (void*)p;
        p += (bytes + 255) & ~(size_t)255;
        return r;
    };
    int*   cnt      = (int*)carve((size_t)N * 4);
    int*   row_start= (int*)carve((size_t)(N + 1) * 4);
    int*   cursor   = (int*)carve((size_t)N * 4);
    int*   partials = (int*)carve(128 * 4);
    int*   srcs     = (int*)carve((size_t)E * 4);
    float* agg      = (float*)carve((size_t)N * 128 * 4);
    float* hA       = (float*)carve((size_t)N * 128 * 4);
    float* hB       = (float*)carve((size_t)N * 128 * 4);
    float* fin      = (float*)carve((size_t)N * 3 * 4);

    const int nchunk = (N + SCAN_CHUNK - 1) / SCAN_CHUNK;

    // CSR build
    hipMemsetAsync(cnt, 0, (size_t)N * 4, stream);
    count_edges<<<(E + 255) / 256, 256, 0, stream>>>(dst, cnt, E);
    scan_partial<<<nchunk, 256, 0, stream>>>(cnt, partials, N);
    scan_partials_excl<<<1, 128, 0, stream>>>(partials, nchunk, row_start, N, E);
    scan_final<<<nchunk, 256, 0, stream>>>(cnt, partials, row_start, cursor, N);
    scatter_edges<<<(E + 255) / 256, 256, 0, stream>>>(src, dst, cursor, srcs, E);

    // layer 0 (K=32)
    aggregate_mean<32><<<(N * 32 + 255) / 256, 256, 0, stream>>>(x, agg, srcs, row_start, N);
    fused_linear2<32><<<(N + 31) / 32, 256, 0, stream>>>(agg, x, Wl0, Wr0, bl0, hA, N);
    // layer 1 (K=128)
    aggregate_mean<128><<<(N * 128 + 255) / 256, 256, 0, stream>>>(hA, agg, srcs, row_start, N);
    fused_linear2<128><<<(N + 31) / 32, 256, 0, stream>>>(agg, hA, Wl1, Wr1, bl1, hB, N);
    // layer 2 (K=128)
    aggregate_mean<128><<<(N * 128 + 255) / 256, 256, 0, stream>>>(hB, agg, srcs, row_start, N);
    fused_linear2<128><<<(N + 31) / 32, 256, 0, stream>>>(agg, hB, Wl2, Wr2, bl2, hA, N);

    // head: h3 = hA
    head_a<<<(N + 3) / 4, 256, 0, stream>>>(hA, Wfc, bfc, fin, N);
    head_b<<<(N * 128 + 255) / 256, 256, 0, stream>>>(fin, Wa1, ba1, hB, N);
    single_linear<<<(N + 31) / 32, 256, 0, stream>>>(hB, Wa2, ba2, agg, N);
    head_d<<<(N + 3) / 4, 256, 0, stream>>>(agg, Wao, bao, fin, N);

    // per-graph mean pool
    pool_kernel<<<G, 256, 0, stream>>>(fin, batch, out, N);
}

// Round 2
// 893.131 us; speedup vs baseline: 1.5810x; 1.5810x over previous
//
#include <hip/hip_runtime.h>

#define SCAN_CHUNK 1024

__device__ __forceinline__ unsigned short f32_to_bf16_rne(float f) {
    unsigned u = __float_as_uint(f);
    unsigned r = (u + 0x7fffu + ((u >> 16) & 1u)) >> 16;
    return (unsigned short)r;
}

__device__ __forceinline__ void accum8(float* acc, uint4 v) {
    unsigned u[4] = {v.x, v.y, v.z, v.w};
#pragma unroll
    for (int q = 0; q < 4; q++) {
        acc[2 * q]     += __uint_as_float(u[q] << 16);
        acc[2 * q + 1] += __uint_as_float(u[q] & 0xffff0000u);
    }
}

// ---------------- CSR build ----------------

__global__ void count_edges(const int* __restrict__ dst, int* __restrict__ cnt, int E) {
    int e = blockIdx.x * 256 + threadIdx.x;
    if (e < E) atomicAdd(&cnt[dst[e]], 1);
}

__global__ void scan_partial(const int* __restrict__ cnt, int* __restrict__ partials, int n) {
    __shared__ int red[256];
    int b = blockIdx.x, t = threadIdx.x;
    int base = b * SCAN_CHUNK;
    int s = 0;
    for (int j = t; j < SCAN_CHUNK; j += 256) {
        int idx = base + j;
        if (idx < n) s += cnt[idx];
    }
    red[t] = s;
    __syncthreads();
    for (int off = 128; off > 0; off >>= 1) {
        if (t < off) red[t] += red[t + off];
        __syncthreads();
    }
    if (t == 0) partials[b] = red[0];
}

// single block of 128 threads; nchunk <= 128
__global__ void scan_partials_excl(int* partials, int nchunk, int* row_start, int n, int E) {
    __shared__ int s[128];
    int t = threadIdx.x;
    int orig = (t < nchunk) ? partials[t] : 0;
    s[t] = orig;
    __syncthreads();
    for (int off = 1; off < 128; off <<= 1) {
        int add = (t >= off) ? s[t - off] : 0;
        __syncthreads();
        s[t] += add;
        __syncthreads();
    }
    if (t < nchunk) partials[t] = s[t] - orig;   // exclusive
    if (t == 0) row_start[n] = E;
}

__global__ void scan_final(const int* __restrict__ cnt, const int* __restrict__ partials,
                           int* __restrict__ row_start, int* __restrict__ cursor, int n) {
    __shared__ int sh[256];
    int b = blockIdx.x, t = threadIdx.x;
    int base = b * SCAN_CHUNK + t * 4;
    int v[4];
    int tot = 0;
#pragma unroll
    for (int j = 0; j < 4; j++) {
        int idx = base + j;
        v[j] = (idx < n) ? cnt[idx] : 0;
        tot += v[j];
    }
    sh[t] = tot;
    __syncthreads();
    for (int off = 1; off < 256; off <<= 1) {
        int add = (t >= off) ? sh[t - off] : 0;
        __syncthreads();
        sh[t] += add;
        __syncthreads();
    }
    int run = partials[b] + sh[t] - tot;   // block-exclusive + thread-exclusive
#pragma unroll
    for (int j = 0; j < 4; j++) {
        int idx = base + j;
        if (idx < n) { row_start[idx] = run; cursor[idx] = run; }
        run += v[j];
    }
}

__global__ void scatter_edges(const int* __restrict__ src, const int* __restrict__ dst,
                              int* __restrict__ cursor, int* __restrict__ sorted_src, int E) {
    int e = blockIdx.x * 256 + threadIdx.x;
    if (e < E) {
        int p = atomicAdd(&cursor[dst[e]], 1);
        sorted_src[p] = src[e];
    }
}

// ---------------- f32 -> bf16 conversion ----------------

__global__ void to_bf16_vec(const float* __restrict__ in, unsigned short* __restrict__ out, int n4) {
    int t = blockIdx.x * 256 + threadIdx.x;
    if (t < n4) {
        float4 v = ((const float4*)in)[t];
        ushort4 o;
        o.x = f32_to_bf16_rne(v.x);
        o.y = f32_to_bf16_rne(v.y);
        o.z = f32_to_bf16_rne(v.z);
        o.w = f32_to_bf16_rne(v.w);
        ((ushort4*)out)[t] = o;
    }
}

// ---------------- aggregation: segment mean via CSR gather, bf16 input, f32 out ---------
// CPN = uint4 (8 bf16) chunks per node row. Thread handles (node, chunk).

template <int CPN>
__launch_bounds__(256)
__global__ void aggregate_mean_bf16(const uint4* __restrict__ hin, float* __restrict__ out,
                                    const int* __restrict__ srcs, const int* __restrict__ rs, int n) {
    int tid = blockIdx.x * 256 + threadIdx.x;
    if (tid >= n * CPN) return;
    int i = tid / CPN;
    int c = tid & (CPN - 1);
    int lo = rs[i], hi = rs[i + 1];
    float acc[8];
#pragma unroll
    for (int q = 0; q < 8; q++) acc[q] = 0.f;
    int e = lo;
    for (; e + 4 <= hi; e += 4) {
        int s0 = srcs[e], s1 = srcs[e + 1], s2 = srcs[e + 2], s3 = srcs[e + 3];
        uint4 v0 = hin[(size_t)s0 * CPN + c];
        uint4 v1 = hin[(size_t)s1 * CPN + c];
        uint4 v2 = hin[(size_t)s2 * CPN + c];
        uint4 v3 = hin[(size_t)s3 * CPN + c];
        accum8(acc, v0);
        accum8(acc, v1);
        accum8(acc, v2);
        accum8(acc, v3);
    }
    for (; e < hi; ++e) {
        uint4 v = hin[(size_t)srcs[e] * CPN + c];
        accum8(acc, v);
    }
    float inv = 1.0f / (float)max(hi - lo, 1);
    float* op = out + (size_t)i * (CPN * 8) + c * 8;
    float4 o0 = make_float4(acc[0] * inv, acc[1] * inv, acc[2] * inv, acc[3] * inv);
    float4 o1 = make_float4(acc[4] * inv, acc[5] * inv, acc[6] * inv, acc[7] * inv);
    ((float4*)op)[0] = o0;
    ((float4*)op)[1] = o1;
}

// ---------------- fused linear: out = relu(A@Wl + H@Wr + b), out width 128 -------------
// A: f32 [n,K] (aggregated means); Hbf: bf16 [n,K] (self term). Writes f32 and/or bf16.

template <int K>
__launch_bounds__(256)
__global__ void fused_linear2(const float* __restrict__ A, const unsigned short* __restrict__ Hbf,
                              const float* __restrict__ Wl, const float* __restrict__ Wr,
                              const float* __restrict__ bias, float* __restrict__ outf,
                              unsigned short* __restrict__ outbf, int n) {
    __shared__ float4 sA[32][K / 4];
    __shared__ uint2 sH[32][K / 4];   // 4 bf16 per uint2
    int b = blockIdx.x, t = threadIdx.x;
    int base = b * 32;
    int rows = min(32, n - base);
    const float4* A4 = (const float4*)(A + (size_t)base * K);
    const uint2* H2 = (const uint2*)(Hbf + (size_t)base * K);
    int nv = rows * (K / 4);
    for (int j = t; j < nv; j += 256) {
        ((float4*)sA)[j] = A4[j];
        ((uint2*)sH)[j] = H2[j];
    }
    __syncthreads();
    int o = t & 127, r = t >> 7;
    float bo = bias[o];
    float acc[16];
#pragma unroll
    for (int m = 0; m < 16; m++) acc[m] = bo;
    for (int kk = 0; kk < K / 4; ++kk) {
        float wl[4], wr[4];
#pragma unroll
        for (int q = 0; q < 4; q++) {
            wl[q] = Wl[(4 * kk + q) * 128 + o];
            wr[q] = Wr[(4 * kk + q) * 128 + o];
        }
#pragma unroll
        for (int m = 0; m < 16; m++) {
            float4 av = sA[r * 16 + m][kk];
            uint2 hu = sH[r * 16 + m][kk];
            float h0 = __uint_as_float(hu.x << 16);
            float h1 = __uint_as_float(hu.x & 0xffff0000u);
            float h2 = __uint_as_float(hu.y << 16);
            float h3 = __uint_as_float(hu.y & 0xffff0000u);
            acc[m] += av.x * wl[0] + av.y * wl[1] + av.z * wl[2] + av.w * wl[3]
                    + h0 * wr[0] + h1 * wr[1] + h2 * wr[2] + h3 * wr[3];
        }
    }
#pragma unroll
    for (int m = 0; m < 16; m++) {
        int node = r * 16 + m;
        if (node < rows) {
            float val = fmaxf(acc[m], 0.f);
            size_t idx = (size_t)(base + node) * 128 + o;
            if (outf) outf[idx] = val;
            if (outbf) outbf[idx] = f32_to_bf16_rne(val);
        }
    }
}

// ---------------- fused head: d1/d3 dots + aux MLP + fin write -------------------------
// one block = 32 nodes

__launch_bounds__(256)
__global__ void head_fused(const float* __restrict__ h3, const float* __restrict__ Wfc,
                           const float* __restrict__ bfc, const float* __restrict__ Wa1,
                           const float* __restrict__ ba1, const float* __restrict__ Wa2,
                           const float* __restrict__ ba2, const float* __restrict__ Wao,
                           const float* __restrict__ bao, float* __restrict__ fin, int n) {
    __shared__ float sH[32 * 128];     // h3 tile, then reused for a1
    __shared__ float sD1[32], sD3[32];
    __shared__ float sRed[2 * 32];
    int b = blockIdx.x, t = threadIdx.x;
    int base = b * 32;
    int rows = min(32, n - base);
    const float4* H4 = (const float4*)(h3 + (size_t)base * 128);
    int nv = rows * 32;
    for (int j = t; j < nv; j += 256) ((float4*)sH)[j] = H4[j];
    __syncthreads();
    // d1/d3: 8 threads per node, 16-feature segments, shuffle-reduce
    {
        int node = t >> 3, seg = t & 7;
        const float* hrow = sH + node * 128 + seg * 16;
        float p1 = 0.f, p3 = 0.f;
#pragma unroll
        for (int q = 0; q < 16; q++) {
            int k = seg * 16 + q;
            float hv = hrow[q];
            p1 += hv * Wfc[k * 3 + 0];
            p3 += hv * Wfc[k * 3 + 2];
        }
        for (int m = 1; m < 8; m <<= 1) {
            p1 += __shfl_xor(p1, m, 64);
            p3 += __shfl_xor(p3, m, 64);
        }
        if ((t & 7) == 0) {
            sD1[node] = p1 + bfc[0];
            sD3[node] = p3 + bfc[2];
        }
    }
    __syncthreads();
    // a1 = relu(d1*Wa1[0,:] + d3*Wa1[1,:] + ba1) into sH (overwrite)
    for (int j = t; j < 32 * 128; j += 256) {
        int node = j >> 7, k = j & 127;
        float a1 = sD1[node] * Wa1[k] + sD3[node] * Wa1[128 + k] + ba1[k];
        sH[j] = fmaxf(a1, 0.f);
    }
    __syncthreads();
    // a2 = relu(a1 @ Wa2 + ba2); aux = a2 . Wao + bao, reduced across o-threads
    int o = t & 127, r = t >> 7;
    float b2 = ba2[o];
    float acc[16];
#pragma unroll
    for (int m = 0; m < 16; m++) acc[m] = b2;
    for (int kk = 0; kk < 32; ++kk) {
        float w[4];
#pragma unroll
        for (int q = 0; q < 4; q++) w[q] = Wa2[(4 * kk + q) * 128 + o];
#pragma unroll
        for (int m = 0; m < 16; m++) {
            float4 av = ((const float4*)sH)[(r * 16 + m) * 32 + kk];
            acc[m] += av.x * w[0] + av.y * w[1] + av.z * w[2] + av.w * w[3];
        }
    }
    float wao = Wao[o];
    float v[16];
#pragma unroll
    for (int m = 0; m < 16; m++) {
        v[m] = fmaxf(acc[m], 0.f) * wao;
        for (int s = 1; s < 64; s <<= 1) v[m] += __shfl_xor(v[m], s, 64);
    }
    int wave = t >> 6;
    int half = wave & 1;
    int lane = t & 63;
    if (lane == 0) {
#pragma unroll
        for (int m = 0; m < 16; m++) sRed[half * 32 + r * 16 + m] = v[m];
    }
    __syncthreads();
    if (t < rows) {
        float aux = sRed[t] + sRed[32 + t] + bao[0];
        fin[(size_t)(base + t) * 3 + 0] = sD1[t];
        fin[(size_t)(base + t) * 3 + 1] = aux;
        fin[(size_t)(base + t) * 3 + 2] = sD3[t];
    }
}

// ---------------- per-graph mean pool (batch sorted, one block per graph) --------------

__global__ void pool_kernel(const float* __restrict__ fin, const int* __restrict__ batch,
                            float* __restrict__ out, int n) {
    int g = blockIdx.x, t = threadIdx.x;
    int lo = 0, hi = n;
    while (lo < hi) { int mid = (lo + hi) >> 1; if (batch[mid] < g) lo = mid + 1; else hi = mid; }
    int start = lo;
    lo = 0; hi = n;
    while (lo < hi) { int mid = (lo + hi) >> 1; if (batch[mid] < g + 1) lo = mid + 1; else hi = mid; }
    int end = lo;
    float s0 = 0.f, s1 = 0.f, s2 = 0.f;
    for (int i = start + t; i < end; i += 256) {
        s0 += fin[(size_t)i * 3 + 0];
        s1 += fin[(size_t)i * 3 + 1];
        s2 += fin[(size_t)i * 3 + 2];
    }
    __shared__ float r0[256], r1[256], r2[256];
    r0[t] = s0; r1[t] = s1; r2[t] = s2;
    __syncthreads();
    for (int off = 128; off > 0; off >>= 1) {
        if (t < off) { r0[t] += r0[t + off]; r1[t] += r1[t + off]; r2[t] += r2[t + off]; }
        __syncthreads();
    }
    if (t == 0) {
        float c = (float)max(end - start, 1);
        out[g * 3 + 0] = r0[0] / c;
        out[g * 3 + 1] = r1[0] / c;
        out[g * 3 + 2] = r2[0] / c;
    }
}

// ---------------- launch ----------------

extern "C" void kernel_launch(void* const* d_in, const int* in_sizes, int n_in,
                              void* d_out, int out_size, void* d_ws, size_t ws_size,
                              hipStream_t stream) {
    const float* x    = (const float*)d_in[0];
    const int*   ei   = (const int*)d_in[1];
    const int*   batch= (const int*)d_in[2];
    const float* Wl0  = (const float*)d_in[3];
    const float* bl0  = (const float*)d_in[4];
    const float* Wr0  = (const float*)d_in[5];
    const float* Wl1  = (const float*)d_in[6];
    const float* bl1  = (const float*)d_in[7];
    const float* Wr1  = (const float*)d_in[8];
    const float* Wl2  = (const float*)d_in[9];
    const float* bl2  = (const float*)d_in[10];
    const float* Wr2  = (const float*)d_in[11];
    const float* Wfc  = (const float*)d_in[12];
    const float* bfc  = (const float*)d_in[13];
    const float* Wa1  = (const float*)d_in[14];
    const float* ba1  = (const float*)d_in[15];
    const float* Wa2  = (const float*)d_in[16];
    const float* ba2  = (const float*)d_in[17];
    const float* Wao  = (const float*)d_in[18];
    const float* bao  = (const float*)d_in[19];

    const int N = in_sizes[0] / 32;
    const int E = in_sizes[1] / 2;
    const int G = out_size / 3;
    const int* src = ei;
    const int* dst = ei + E;
    float* out = (float*)d_out;

    // workspace carve-up (256B-aligned)
    char* p = (char*)d_ws;
    auto carve = [&](size_t bytes) {
        void* r = (void*)p;
        p += (bytes + 255) & ~(size_t)255;
        return r;
    };
    int*            cnt      = (int*)carve((size_t)N * 4);
    int*            row_start= (int*)carve((size_t)(N + 1) * 4);
    int*            cursor   = (int*)carve((size_t)N * 4);
    int*            partials = (int*)carve(128 * 4);
    int*            srcs     = (int*)carve((size_t)E * 4);
    float*          agg      = (float*)carve((size_t)N * 128 * 4);
    float*          h3f      = (float*)carve((size_t)N * 128 * 4);
    unsigned short* xbf      = (unsigned short*)carve((size_t)N * 32 * 2);
    unsigned short* hbf0     = (unsigned short*)carve((size_t)N * 128 * 2);
    unsigned short* hbf1     = (unsigned short*)carve((size_t)N * 128 * 2);
    float*          fin      = (float*)carve((size_t)N * 3 * 4);

    const int nchunk = (N + SCAN_CHUNK - 1) / SCAN_CHUNK;

    // x -> bf16
    to_bf16_vec<<<(N * 32 / 4 + 255) / 256, 256, 0, stream>>>(x, xbf, N * 32 / 4);

    // CSR build
    hipMemsetAsync(cnt, 0, (size_t)N * 4, stream);
    count_edges<<<(E + 255) / 256, 256, 0, stream>>>(dst, cnt, E);
    scan_partial<<<nchunk, 256, 0, stream>>>(cnt, partials, N);
    scan_partials_excl<<<1, 128, 0, stream>>>(partials, nchunk, row_start, N, E);
    scan_final<<<nchunk, 256, 0, stream>>>(cnt, partials, row_start, cursor, N);
    scatter_edges<<<(E + 255) / 256, 256, 0, stream>>>(src, dst, cursor, srcs, E);

    // layer 0 (K=32): agg over xbf; self term = xbf; out bf16 only
    aggregate_mean_bf16<4><<<(N * 4 + 255) / 256, 256, 0, stream>>>(
        (const uint4*)xbf, agg, srcs, row_start, N);
    fused_linear2<32><<<(N + 31) / 32, 256, 0, stream>>>(
        agg, xbf, Wl0, Wr0, bl0, (float*)nullptr, hbf0, N);
    // layer 1 (K=128)
    aggregate_mean_bf16<16><<<(N * 16 + 255) / 256, 256, 0, stream>>>(
        (const uint4*)hbf0, agg, srcs, row_start, N);
    fused_linear2<128><<<(N + 31) / 32, 256, 0, stream>>>(
        agg, hbf0, Wl1, Wr1, bl1, (float*)nullptr, hbf1, N);
    // layer 2 (K=128): out f32 for the head
    aggregate_mean_bf16<16><<<(N * 16 + 255) / 256, 256, 0, stream>>>(
        (const uint4*)hbf1, agg, srcs, row_start, N);
    fused_linear2<128><<<(N + 31) / 32, 256, 0, stream>>>(
        agg, hbf1, Wl2, Wr2, bl2, h3f, (unsigned short*)nullptr, N);

    // fused head -> fin
    head_fused<<<(N + 31) / 32, 256, 0, stream>>>(
        h3f, Wfc, bfc, Wa1, ba1, Wa2, ba2, Wao, bao, fin, N);

    // per-graph mean pool
    pool_kernel<<<G, 256, 0, stream>>>(fin, batch, out, N);
}

// Round 3
// 620.519 us; speedup vs baseline: 2.2756x; 1.4393x over previous
//
#include <hip/hip_runtime.h>

#define SCAN_CHUNK 1024
typedef unsigned short ushortT;
typedef __attribute__((ext_vector_type(8))) short short8;
typedef __attribute__((ext_vector_type(4))) float float4v;

__device__ __forceinline__ unsigned short f32_to_bf16_rne(float f) {
    unsigned u = __float_as_uint(f);
    unsigned r = (u + 0x7fffu + ((u >> 16) & 1u)) >> 16;
    return (unsigned short)r;
}

__device__ __forceinline__ void accum8(float* acc, uint4 v) {
    unsigned u[4] = {v.x, v.y, v.z, v.w};
#pragma unroll
    for (int q = 0; q < 4; q++) {
        acc[2 * q]     += __uint_as_float(u[q] << 16);
        acc[2 * q + 1] += __uint_as_float(u[q] & 0xffff0000u);
    }
}

// ---------------- CSR build ----------------

__global__ void count_edges(const int* __restrict__ dst, int* __restrict__ cnt, int E) {
    int e = blockIdx.x * 256 + threadIdx.x;
    if (e < E) atomicAdd(&cnt[dst[e]], 1);
}

__global__ void scan_partial(const int* __restrict__ cnt, int* __restrict__ partials, int n) {
    __shared__ int red[256];
    int b = blockIdx.x, t = threadIdx.x;
    int base = b * SCAN_CHUNK;
    int s = 0;
    for (int j = t; j < SCAN_CHUNK; j += 256) {
        int idx = base + j;
        if (idx < n) s += cnt[idx];
    }
    red[t] = s;
    __syncthreads();
    for (int off = 128; off > 0; off >>= 1) {
        if (t < off) red[t] += red[t + off];
        __syncthreads();
    }
    if (t == 0) partials[b] = red[0];
}

__global__ void scan_partials_excl(int* partials, int nchunk, int* row_start, int n, int E) {
    __shared__ int s[128];
    int t = threadIdx.x;
    int orig = (t < nchunk) ? partials[t] : 0;
    s[t] = orig;
    __syncthreads();
    for (int off = 1; off < 128; off <<= 1) {
        int add = (t >= off) ? s[t - off] : 0;
        __syncthreads();
        s[t] += add;
        __syncthreads();
    }
    if (t < nchunk) partials[t] = s[t] - orig;   // exclusive
    if (t == 0) row_start[n] = E;
}

__global__ void scan_final(const int* __restrict__ cnt, const int* __restrict__ partials,
                           int* __restrict__ row_start, int* __restrict__ cursor, int n) {
    __shared__ int sh[256];
    int b = blockIdx.x, t = threadIdx.x;
    int base = b * SCAN_CHUNK + t * 4;
    int v[4];
    int tot = 0;
#pragma unroll
    for (int j = 0; j < 4; j++) {
        int idx = base + j;
        v[j] = (idx < n) ? cnt[idx] : 0;
        tot += v[j];
    }
    sh[t] = tot;
    __syncthreads();
    for (int off = 1; off < 256; off <<= 1) {
        int add = (t >= off) ? sh[t - off] : 0;
        __syncthreads();
        sh[t] += add;
        __syncthreads();
    }
    int run = partials[b] + sh[t] - tot;
#pragma unroll
    for (int j = 0; j < 4; j++) {
        int idx = base + j;
        if (idx < n) { row_start[idx] = run; cursor[idx] = run; }
        run += v[j];
    }
}

__global__ void scatter_edges(const int* __restrict__ src, const int* __restrict__ dst,
                              int* __restrict__ cursor, int* __restrict__ sorted_src, int E) {
    int e = blockIdx.x * 256 + threadIdx.x;
    if (e < E) {
        int p = atomicAdd(&cursor[dst[e]], 1);
        sorted_src[p] = src[e];
    }
}

// ---------------- f32 -> bf16 ----------------

__global__ void to_bf16_vec(const float* __restrict__ in, ushortT* __restrict__ out, int n4) {
    int t = blockIdx.x * 256 + threadIdx.x;
    if (t < n4) {
        float4 v = ((const float4*)in)[t];
        ushort4 o;
        o.x = f32_to_bf16_rne(v.x);
        o.y = f32_to_bf16_rne(v.y);
        o.z = f32_to_bf16_rne(v.z);
        o.w = f32_to_bf16_rne(v.w);
        ((ushort4*)out)[t] = o;
    }
}

// ---------------- weight prep: Wt[col][ (k + 8*col) % KT ] = bf16(Wcat[k][col]) ----------

__global__ void prep_wt(const float* __restrict__ Wl, const float* __restrict__ Wr,
                        ushortT* __restrict__ Wt, int KH) {
    int KT = 2 * KH;
    int tid = blockIdx.x * 256 + threadIdx.x;
    if (tid >= 128 * KT) return;
    int col = tid / KT, k = tid - col * KT;
    float v = (k < KH) ? Wl[k * 128 + col] : Wr[(k - KH) * 128 + col];
    int pos = (k + 8 * col) & (KT - 1);
    Wt[col * KT + pos] = f32_to_bf16_rne(v);
}

// ---------------- aggregation: segment mean via CSR gather, bf16 in, bf16 out -----------

template <int CPN>
__launch_bounds__(256)
__global__ void aggregate_mean_bf16(const uint4* __restrict__ hin, ushortT* __restrict__ out,
                                    const int* __restrict__ srcs, const int* __restrict__ rs, int n) {
    int tid = blockIdx.x * 256 + threadIdx.x;
    if (tid >= n * CPN) return;
    int i = tid / CPN;
    int c = tid & (CPN - 1);
    int lo = rs[i], hi = rs[i + 1];
    float acc[8];
#pragma unroll
    for (int q = 0; q < 8; q++) acc[q] = 0.f;
    int e = lo;
    for (; e + 4 <= hi; e += 4) {
        int s0 = srcs[e], s1 = srcs[e + 1], s2 = srcs[e + 2], s3 = srcs[e + 3];
        uint4 v0 = hin[(size_t)s0 * CPN + c];
        uint4 v1 = hin[(size_t)s1 * CPN + c];
        uint4 v2 = hin[(size_t)s2 * CPN + c];
        uint4 v3 = hin[(size_t)s3 * CPN + c];
        accum8(acc, v0);
        accum8(acc, v1);
        accum8(acc, v2);
        accum8(acc, v3);
    }
    for (; e < hi; ++e) {
        uint4 v = hin[(size_t)srcs[e] * CPN + c];
        accum8(acc, v);
    }
    float inv = 1.0f / (float)max(hi - lo, 1);
    uint4 o;
    o.x = (unsigned)f32_to_bf16_rne(acc[0] * inv) | ((unsigned)f32_to_bf16_rne(acc[1] * inv) << 16);
    o.y = (unsigned)f32_to_bf16_rne(acc[2] * inv) | ((unsigned)f32_to_bf16_rne(acc[3] * inv) << 16);
    o.z = (unsigned)f32_to_bf16_rne(acc[4] * inv) | ((unsigned)f32_to_bf16_rne(acc[5] * inv) << 16);
    o.w = (unsigned)f32_to_bf16_rne(acc[6] * inv) | ((unsigned)f32_to_bf16_rne(acc[7] * inv) << 16);
    ((uint4*)out)[(size_t)i * CPN + c] = o;
}

// ---------------- MFMA GEMM: out = relu([Am | Ah] @ [Wl;Wr] + bias) --------------------
// Am, Ah: bf16 [n][KH] row-major. Wt: bf16 [128][KT] swizzled (prep_wt). KT = 2*KH.
// Block = 256 thr = 4 waves; tile = 128 rows x 128 cols; wave = 32 rows.

template <int KH, bool OUT_BF16>
__launch_bounds__(256, 2)
__global__ void gemm_mfma(const ushortT* __restrict__ Am, const ushortT* __restrict__ Ah,
                          const ushortT* __restrict__ Wt, const float* __restrict__ bias,
                          float* __restrict__ outf, ushortT* __restrict__ outbf, int n) {
    constexpr int KT = 2 * KH;
    __shared__ ushortT sW[128 * KT];
    int t = threadIdx.x;
    // stage swizzled W^T (linear copy)
    constexpr int TOT16 = 128 * KT * 2 / 16;
    {
        const uint4* Wg = (const uint4*)Wt;
        uint4* Ws = (uint4*)sW;
        for (int j = t; j < TOT16; j += 256) Ws[j] = Wg[j];
    }
    __syncthreads();
    int wv = t >> 6, lane = t & 63;
    int q = lane >> 4, cid = lane & 15;
    int rbase = blockIdx.x * 128 + wv * 32;
    int r0 = rbase + cid, r1 = r0 + 16;
    int r0c = min(r0, n - 1), r1c = min(r1, n - 1);
    float4v acc[2][8];
#pragma unroll
    for (int i = 0; i < 2; i++)
#pragma unroll
        for (int j = 0; j < 8; j++) acc[i][j] = (float4v){0.f, 0.f, 0.f, 0.f};
    int swz = q * 8 + 8 * cid;
#pragma unroll
    for (int ks = 0; ks < KT / 32; ++ks) {
        int kk = ks * 32;
        const ushortT* abase = (kk < KH) ? Am : Ah;
        int kc = (kk < KH) ? kk : kk - KH;
        short8 a0 = *(const short8*)(abase + (size_t)r0c * KH + kc + q * 8);
        short8 a1 = *(const short8*)(abase + (size_t)r1c * KH + kc + q * 8);
#pragma unroll
        for (int j = 0; j < 8; ++j) {
            int col = j * 16 + cid;
            int p = (kk + swz + j * 128) & (KT - 1);
            short8 b = *(const short8*)(sW + col * KT + p);
            acc[0][j] = __builtin_amdgcn_mfma_f32_16x16x32_bf16(a0, b, acc[0][j], 0, 0, 0);
            acc[1][j] = __builtin_amdgcn_mfma_f32_16x16x32_bf16(a1, b, acc[1][j], 0, 0, 0);
        }
    }
    // epilogue: row = rbase + i*16 + q*4 + rr ; col = j*16 + cid
    float bo[8];
#pragma unroll
    for (int j = 0; j < 8; ++j) bo[j] = bias[j * 16 + cid];
#pragma unroll
    for (int i = 0; i < 2; ++i) {
#pragma unroll
        for (int rr = 0; rr < 4; ++rr) {
            int row = rbase + i * 16 + q * 4 + rr;
            if (row < n) {
#pragma unroll
                for (int j = 0; j < 8; ++j) {
                    int col = j * 16 + cid;
                    float v = fmaxf(acc[i][j][rr] + bo[j], 0.f);
                    if (OUT_BF16) outbf[(size_t)row * 128 + col] = f32_to_bf16_rne(v);
                    else          outf[(size_t)row * 128 + col] = v;
                }
            }
        }
    }
}

// ---------------- fused head ----------------

__launch_bounds__(256)
__global__ void head_fused(const float* __restrict__ h3, const float* __restrict__ Wfc,
                           const float* __restrict__ bfc, const float* __restrict__ Wa1,
                           const float* __restrict__ ba1, const float* __restrict__ Wa2,
                           const float* __restrict__ ba2, const float* __restrict__ Wao,
                           const float* __restrict__ bao, float* __restrict__ fin, int n) {
    __shared__ float sH[32 * 128];
    __shared__ float sD1[32], sD3[32];
    __shared__ float sRed[2 * 32];
    int b = blockIdx.x, t = threadIdx.x;
    int base = b * 32;
    int rows = min(32, n - base);
    const float4* H4 = (const float4*)(h3 + (size_t)base * 128);
    int nv = rows * 32;
    for (int j = t; j < nv; j += 256) ((float4*)sH)[j] = H4[j];
    __syncthreads();
    {
        int node = t >> 3, seg = t & 7;
        const float* hrow = sH + node * 128 + seg * 16;
        float p1 = 0.f, p3 = 0.f;
#pragma unroll
        for (int q = 0; q < 16; q++) {
            int k = seg * 16 + q;
            float hv = hrow[q];
            p1 += hv * Wfc[k * 3 + 0];
            p3 += hv * Wfc[k * 3 + 2];
        }
        for (int m = 1; m < 8; m <<= 1) {
            p1 += __shfl_xor(p1, m, 64);
            p3 += __shfl_xor(p3, m, 64);
        }
        if ((t & 7) == 0) {
            sD1[node] = p1 + bfc[0];
            sD3[node] = p3 + bfc[2];
        }
    }
    __syncthreads();
    for (int j = t; j < 32 * 128; j += 256) {
        int node = j >> 7, k = j & 127;
        float a1 = sD1[node] * Wa1[k] + sD3[node] * Wa1[128 + k] + ba1[k];
        sH[j] = fmaxf(a1, 0.f);
    }
    __syncthreads();
    int o = t & 127, r = t >> 7;
    float b2 = ba2[o];
    float acc[16];
#pragma unroll
    for (int m = 0; m < 16; m++) acc[m] = b2;
    for (int kk = 0; kk < 32; ++kk) {
        float w[4];
#pragma unroll
        for (int q = 0; q < 4; q++) w[q] = Wa2[(4 * kk + q) * 128 + o];
#pragma unroll
        for (int m = 0; m < 16; m++) {
            float4 av = ((const float4*)sH)[(r * 16 + m) * 32 + kk];
            acc[m] += av.x * w[0] + av.y * w[1] + av.z * w[2] + av.w * w[3];
        }
    }
    float wao = Wao[o];
    float v[16];
#pragma unroll
    for (int m = 0; m < 16; m++) {
        v[m] = fmaxf(acc[m], 0.f) * wao;
        for (int s = 1; s < 64; s <<= 1) v[m] += __shfl_xor(v[m], s, 64);
    }
    int wave = t >> 6;
    int half = wave & 1;
    int lane = t & 63;
    if (lane == 0) {
#pragma unroll
        for (int m = 0; m < 16; m++) sRed[half * 32 + r * 16 + m] = v[m];
    }
    __syncthreads();
    if (t < rows) {
        float aux = sRed[t] + sRed[32 + t] + bao[0];
        fin[(size_t)(base + t) * 3 + 0] = sD1[t];
        fin[(size_t)(base + t) * 3 + 1] = aux;
        fin[(size_t)(base + t) * 3 + 2] = sD3[t];
    }
}

// ---------------- per-graph mean pool ----------------

__global__ void pool_kernel(const float* __restrict__ fin, const int* __restrict__ batch,
                            float* __restrict__ out, int n) {
    int g = blockIdx.x, t = threadIdx.x;
    int lo = 0, hi = n;
    while (lo < hi) { int mid = (lo + hi) >> 1; if (batch[mid] < g) lo = mid + 1; else hi = mid; }
    int start = lo;
    lo = 0; hi = n;
    while (lo < hi) { int mid = (lo + hi) >> 1; if (batch[mid] < g + 1) lo = mid + 1; else hi = mid; }
    int end = lo;
    float s0 = 0.f, s1 = 0.f, s2 = 0.f;
    for (int i = start + t; i < end; i += 256) {
        s0 += fin[(size_t)i * 3 + 0];
        s1 += fin[(size_t)i * 3 + 1];
        s2 += fin[(size_t)i * 3 + 2];
    }
    __shared__ float r0[256], r1[256], r2[256];
    r0[t] = s0; r1[t] = s1; r2[t] = s2;
    __syncthreads();
    for (int off = 128; off > 0; off >>= 1) {
        if (t < off) { r0[t] += r0[t + off]; r1[t] += r1[t + off]; r2[t] += r2[t + off]; }
        __syncthreads();
    }
    if (t == 0) {
        float c = (float)max(end - start, 1);
        out[g * 3 + 0] = r0[0] / c;
        out[g * 3 + 1] = r1[0] / c;
        out[g * 3 + 2] = r2[0] / c;
    }
}

// ---------------- launch ----------------

extern "C" void kernel_launch(void* const* d_in, const int* in_sizes, int n_in,
                              void* d_out, int out_size, void* d_ws, size_t ws_size,
                              hipStream_t stream) {
    const float* x    = (const float*)d_in[0];
    const int*   ei   = (const int*)d_in[1];
    const int*   batch= (const int*)d_in[2];
    const float* Wl0  = (const float*)d_in[3];
    const float* bl0  = (const float*)d_in[4];
    const float* Wr0  = (const float*)d_in[5];
    const float* Wl1  = (const float*)d_in[6];
    const float* bl1  = (const float*)d_in[7];
    const float* Wr1  = (const float*)d_in[8];
    const float* Wl2  = (const float*)d_in[9];
    const float* bl2  = (const float*)d_in[10];
    const float* Wr2  = (const float*)d_in[11];
    const float* Wfc  = (const float*)d_in[12];
    const float* bfc  = (const float*)d_in[13];
    const float* Wa1  = (const float*)d_in[14];
    const float* ba1  = (const float*)d_in[15];
    const float* Wa2  = (const float*)d_in[16];
    const float* ba2  = (const float*)d_in[17];
    const float* Wao  = (const float*)d_in[18];
    const float* bao  = (const float*)d_in[19];

    const int N = in_sizes[0] / 32;
    const int E = in_sizes[1] / 2;
    const int G = out_size / 3;
    const int* src = ei;
    const int* dst = ei + E;
    float* out = (float*)d_out;

    char* p = (char*)d_ws;
    auto carve = [&](size_t bytes) {
        void* r = (void*)p;
        p += (bytes + 255) & ~(size_t)255;
        return r;
    };
    int*     cnt      = (int*)carve((size_t)N * 4);
    int*     row_start= (int*)carve((size_t)(N + 1) * 4);
    int*     cursor   = (int*)carve((size_t)N * 4);
    int*     partials = (int*)carve(128 * 4);
    int*     srcs     = (int*)carve((size_t)E * 4);
    ushortT* aggbf    = (ushortT*)carve((size_t)N * 128 * 2);
    float*   h3f      = (float*)carve((size_t)N * 128 * 4);
    ushortT* xbf      = (ushortT*)carve((size_t)N * 32 * 2);
    ushortT* hbf0     = (ushortT*)carve((size_t)N * 128 * 2);
    ushortT* hbf1     = (ushortT*)carve((size_t)N * 128 * 2);
    float*   fin      = (float*)carve((size_t)N * 3 * 4);
    ushortT* Wt0      = (ushortT*)carve((size_t)128 * 64 * 2);
    ushortT* Wt1      = (ushortT*)carve((size_t)128 * 256 * 2);
    ushortT* Wt2      = (ushortT*)carve((size_t)128 * 256 * 2);

    const int nchunk = (N + SCAN_CHUNK - 1) / SCAN_CHUNK;
    const int gemm_grid = (N + 127) / 128;

    // x -> bf16 ; weight prep
    to_bf16_vec<<<(N * 32 / 4 + 255) / 256, 256, 0, stream>>>(x, xbf, N * 32 / 4);
    prep_wt<<<(128 * 64 + 255) / 256, 256, 0, stream>>>(Wl0, Wr0, Wt0, 32);
    prep_wt<<<(128 * 256 + 255) / 256, 256, 0, stream>>>(Wl1, Wr1, Wt1, 128);
    prep_wt<<<(128 * 256 + 255) / 256, 256, 0, stream>>>(Wl2, Wr2, Wt2, 128);

    // CSR build
    hipMemsetAsync(cnt, 0, (size_t)N * 4, stream);
    count_edges<<<(E + 255) / 256, 256, 0, stream>>>(dst, cnt, E);
    scan_partial<<<nchunk, 256, 0, stream>>>(cnt, partials, N);
    scan_partials_excl<<<1, 128, 0, stream>>>(partials, nchunk, row_start, N, E);
    scan_final<<<nchunk, 256, 0, stream>>>(cnt, partials, row_start, cursor, N);
    scatter_edges<<<(E + 255) / 256, 256, 0, stream>>>(src, dst, cursor, srcs, E);

    // layer 0 (KH=32)
    aggregate_mean_bf16<4><<<(N * 4 + 255) / 256, 256, 0, stream>>>(
        (const uint4*)xbf, aggbf, srcs, row_start, N);
    gemm_mfma<32, true><<<gemm_grid, 256, 0, stream>>>(
        aggbf, xbf, Wt0, bl0, (float*)nullptr, hbf0, N);
    // layer 1 (KH=128)
    aggregate_mean_bf16<16><<<(N * 16 + 255) / 256, 256, 0, stream>>>(
        (const uint4*)hbf0, aggbf, srcs, row_start, N);
    gemm_mfma<128, true><<<gemm_grid, 256, 0, stream>>>(
        aggbf, hbf0, Wt1, bl1, (float*)nullptr, hbf1, N);
    // layer 2 (KH=128): f32 out for the head
    aggregate_mean_bf16<16><<<(N * 16 + 255) / 256, 256, 0, stream>>>(
        (const uint4*)hbf1, aggbf, srcs, row_start, N);
    gemm_mfma<128, false><<<gemm_grid, 256, 0, stream>>>(
        aggbf, hbf1, Wt2, bl2, h3f, (ushortT*)nullptr, N);

    // fused head -> fin
    head_fused<<<(N + 31) / 32, 256, 0, stream>>>(
        h3f, Wfc, bfc, Wa1, ba1, Wa2, ba2, Wao, bao, fin, N);

    // per-graph mean pool
    pool_kernel<<<G, 256, 0, stream>>>(fin, batch, out, N);
}

// Round 4
// 475.096 us; speedup vs baseline: 2.9722x; 1.3061x over previous
//
#include <hip/hip_runtime.h>

#define NR 128        // dst nodes per bucket
#define PART_CH 4096  // edges per partition/count block
typedef unsigned short ushortT;
typedef __attribute__((ext_vector_type(8))) short short8;
typedef __attribute__((ext_vector_type(4))) float float4v;

__device__ __forceinline__ unsigned short f32_to_bf16_rne(float f) {
    unsigned u = __float_as_uint(f);
    unsigned r = (u + 0x7fffu + ((u >> 16) & 1u)) >> 16;
    return (unsigned short)r;
}

__device__ __forceinline__ void accum8(float* acc, uint4 v) {
    unsigned u[4] = {v.x, v.y, v.z, v.w};
#pragma unroll
    for (int q = 0; q < 4; q++) {
        acc[2 * q]     += __uint_as_float(u[q] << 16);
        acc[2 * q + 1] += __uint_as_float(u[q] & 0xffff0000u);
    }
}

// ---------------- CSR build: bucketed counting sort ----------------

__launch_bounds__(256)
__global__ void bucket_count(const int* __restrict__ dst, int* __restrict__ bcnt, int E, int NB) {
    __shared__ int h[1024];
    int t = threadIdx.x;
    for (int j = t; j < NB; j += 256) h[j] = 0;
    __syncthreads();
    int e0 = blockIdx.x * PART_CH;
    int e1 = min(e0 + PART_CH, E);
    for (int e = e0 + t; e < e1; e += 256) atomicAdd(&h[dst[e] >> 7], 1);
    __syncthreads();
    for (int j = t; j < NB; j += 256) {
        int v = h[j];
        if (v) atomicAdd(&bcnt[j], v);
    }
}

// single block: exclusive scan of NB (<=1024) bucket counts
__launch_bounds__(256)
__global__ void bucket_scan(const int* __restrict__ bcnt, int* __restrict__ bstart,
                            int* __restrict__ gcur, int NB, int E) {
    __shared__ int sh[256];
    int t = threadIdx.x;
    int v[4];
    int tot = 0;
#pragma unroll
    for (int j = 0; j < 4; j++) {
        int idx = t * 4 + j;
        v[j] = (idx < NB) ? bcnt[idx] : 0;
        tot += v[j];
    }
    sh[t] = tot;
    __syncthreads();
    for (int off = 1; off < 256; off <<= 1) {
        int add = (t >= off) ? sh[t - off] : 0;
        __syncthreads();
        sh[t] += add;
        __syncthreads();
    }
    int run = sh[t] - tot;
#pragma unroll
    for (int j = 0; j < 4; j++) {
        int idx = t * 4 + j;
        if (idx < NB) { bstart[idx] = run; gcur[idx] = run; }
        run += v[j];
    }
    if (t == 0) bstart[NB] = E;
}

// partition edges into buckets; packed record = src | (dst&127)<<17  (src < 2^17)
__launch_bounds__(256)
__global__ void partition_edges(const int* __restrict__ src, const int* __restrict__ dst,
                                int* __restrict__ gcur, unsigned* __restrict__ packed,
                                int E, int NB) {
    __shared__ int hist[1024];
    __shared__ int base[1024];
    int t = threadIdx.x;
    int e0 = blockIdx.x * PART_CH;
    int e1 = min(e0 + PART_CH, E);
    for (int j = t; j < NB; j += 256) hist[j] = 0;
    __syncthreads();
    for (int e = e0 + t; e < e1; e += 256) atomicAdd(&hist[dst[e] >> 7], 1);
    __syncthreads();
    for (int j = t; j < NB; j += 256) {
        int h = hist[j];
        base[j] = h ? atomicAdd(&gcur[j], h) : 0;
    }
    __syncthreads();
    for (int j = t; j < NB; j += 256) hist[j] = base[j];
    __syncthreads();
    for (int e = e0 + t; e < e1; e += 256) {
        int d = dst[e];
        int b = d >> 7;
        int pos = atomicAdd(&hist[b], 1);
        packed[pos] = (unsigned)src[e] | ((unsigned)(d & (NR - 1)) << 17);
    }
}

// one block per bucket: local histogram + scan -> row_start, then scatter srcs
__launch_bounds__(256)
__global__ void bucket_sort(const unsigned* __restrict__ packed, const int* __restrict__ bstart,
                            int* __restrict__ row_start, int* __restrict__ srcs, int N) {
    __shared__ int cnt[NR];
    __shared__ int sc[NR];
    __shared__ int cur[NR];
    int b = blockIdx.x, t = threadIdx.x;
    int nb0 = b * NR;
    int nnode = min(NR, N - nb0);
    int lo = bstart[b], hi = bstart[b + 1];
    if (t < NR) cnt[t] = 0;
    __syncthreads();
    for (int j = lo + t; j < hi; j += 256) atomicAdd(&cnt[packed[j] >> 17], 1);
    __syncthreads();
    if (t < NR) sc[t] = cnt[t];
    __syncthreads();
    for (int off = 1; off < NR; off <<= 1) {
        int add = (t >= off && t < NR) ? sc[t - off] : 0;
        __syncthreads();
        if (t < NR) sc[t] += add;
        __syncthreads();
    }
    if (t < nnode) {
        int s = lo + sc[t] - cnt[t];   // exclusive
        row_start[nb0 + t] = s;
        cur[t] = s;
    }
    if (t == 0 && nb0 + nnode == N) row_start[N] = hi;
    __syncthreads();
    for (int j = lo + t; j < hi; j += 256) {
        unsigned pk = packed[j];
        int pos = atomicAdd(&cur[pk >> 17], 1);
        srcs[pos] = (int)(pk & 0x1FFFFu);
    }
}

// ---------------- f32 -> bf16 ----------------

__global__ void to_bf16_vec(const float* __restrict__ in, ushortT* __restrict__ out, int n4) {
    int t = blockIdx.x * 256 + threadIdx.x;
    if (t < n4) {
        float4 v = ((const float4*)in)[t];
        ushort4 o;
        o.x = f32_to_bf16_rne(v.x);
        o.y = f32_to_bf16_rne(v.y);
        o.z = f32_to_bf16_rne(v.z);
        o.w = f32_to_bf16_rne(v.w);
        ((ushort4*)out)[t] = o;
    }
}

// ---------------- weight prep: Wt[col][(k + 8*col) % KT] = bf16(Wcat[k][col]) ----------

__global__ void prep_wt(const float* __restrict__ Wl, const float* __restrict__ Wr,
                        ushortT* __restrict__ Wt, int KH) {
    int KT = 2 * KH;
    int tid = blockIdx.x * 256 + threadIdx.x;
    if (tid >= 128 * KT) return;
    int col = tid / KT, k = tid - col * KT;
    float v = (k < KH) ? Wl[k * 128 + col] : Wr[(k - KH) * 128 + col];
    int pos = (k + 8 * col) & (KT - 1);
    Wt[col * KT + pos] = f32_to_bf16_rne(v);
}

// ---------------- aggregation: segment mean via CSR gather, bf16 in, bf16 out -----------
// CPN uint4 chunks per row; each thread owns 2 chunks (c and c+CPN/2) of one node.

template <int CPN>
__launch_bounds__(256)
__global__ void aggregate_mean_bf16(const uint4* __restrict__ hin, ushortT* __restrict__ out,
                                    const int* __restrict__ srcs, const int* __restrict__ rs, int n) {
    constexpr int TPN = CPN / 2;
    int tid = blockIdx.x * 256 + threadIdx.x;
    if (tid >= n * TPN) return;
    int i = tid / TPN;
    int c = tid & (TPN - 1);
    int lo = rs[i], hi = rs[i + 1];
    float acc0[8], acc1[8];
#pragma unroll
    for (int q = 0; q < 8; q++) { acc0[q] = 0.f; acc1[q] = 0.f; }
    int e = lo;
    for (; e + 4 <= hi; e += 4) {
        int s0 = srcs[e], s1 = srcs[e + 1], s2 = srcs[e + 2], s3 = srcs[e + 3];
        uint4 a0 = hin[(size_t)s0 * CPN + c];
        uint4 b0 = hin[(size_t)s0 * CPN + c + TPN];
        uint4 a1 = hin[(size_t)s1 * CPN + c];
        uint4 b1 = hin[(size_t)s1 * CPN + c + TPN];
        uint4 a2 = hin[(size_t)s2 * CPN + c];
        uint4 b2 = hin[(size_t)s2 * CPN + c + TPN];
        uint4 a3 = hin[(size_t)s3 * CPN + c];
        uint4 b3 = hin[(size_t)s3 * CPN + c + TPN];
        accum8(acc0, a0); accum8(acc1, b0);
        accum8(acc0, a1); accum8(acc1, b1);
        accum8(acc0, a2); accum8(acc1, b2);
        accum8(acc0, a3); accum8(acc1, b3);
    }
    for (; e < hi; ++e) {
        int s = srcs[e];
        accum8(acc0, hin[(size_t)s * CPN + c]);
        accum8(acc1, hin[(size_t)s * CPN + c + TPN]);
    }
    float inv = 1.0f / (float)max(hi - lo, 1);
    uint4 o0, o1;
    o0.x = (unsigned)f32_to_bf16_rne(acc0[0] * inv) | ((unsigned)f32_to_bf16_rne(acc0[1] * inv) << 16);
    o0.y = (unsigned)f32_to_bf16_rne(acc0[2] * inv) | ((unsigned)f32_to_bf16_rne(acc0[3] * inv) << 16);
    o0.z = (unsigned)f32_to_bf16_rne(acc0[4] * inv) | ((unsigned)f32_to_bf16_rne(acc0[5] * inv) << 16);
    o0.w = (unsigned)f32_to_bf16_rne(acc0[6] * inv) | ((unsigned)f32_to_bf16_rne(acc0[7] * inv) << 16);
    o1.x = (unsigned)f32_to_bf16_rne(acc1[0] * inv) | ((unsigned)f32_to_bf16_rne(acc1[1] * inv) << 16);
    o1.y = (unsigned)f32_to_bf16_rne(acc1[2] * inv) | ((unsigned)f32_to_bf16_rne(acc1[3] * inv) << 16);
    o1.z = (unsigned)f32_to_bf16_rne(acc1[4] * inv) | ((unsigned)f32_to_bf16_rne(acc1[5] * inv) << 16);
    o1.w = (unsigned)f32_to_bf16_rne(acc1[6] * inv) | ((unsigned)f32_to_bf16_rne(acc1[7] * inv) << 16);
    ((uint4*)out)[(size_t)i * CPN + c] = o0;
    ((uint4*)out)[(size_t)i * CPN + c + TPN] = o1;
}

// ---------------- MFMA GEMM: out = relu([Am | Ah] @ [Wl;Wr] + bias) --------------------

template <int KH, bool OUT_BF16>
__launch_bounds__(256, 2)
__global__ void gemm_mfma(const ushortT* __restrict__ Am, const ushortT* __restrict__ Ah,
                          const ushortT* __restrict__ Wt, const float* __restrict__ bias,
                          float* __restrict__ outf, ushortT* __restrict__ outbf, int n) {
    constexpr int KT = 2 * KH;
    __shared__ ushortT sW[128 * KT];
    int t = threadIdx.x;
    constexpr int TOT16 = 128 * KT * 2 / 16;
    {
        const uint4* Wg = (const uint4*)Wt;
        uint4* Ws = (uint4*)sW;
        for (int j = t; j < TOT16; j += 256) Ws[j] = Wg[j];
    }
    __syncthreads();
    int wv = t >> 6, lane = t & 63;
    int q = lane >> 4, cid = lane & 15;
    int rbase = blockIdx.x * 128 + wv * 32;
    int r0 = rbase + cid, r1 = r0 + 16;
    int r0c = min(r0, n - 1), r1c = min(r1, n - 1);
    float4v acc[2][8];
#pragma unroll
    for (int i = 0; i < 2; i++)
#pragma unroll
        for (int j = 0; j < 8; j++) acc[i][j] = (float4v){0.f, 0.f, 0.f, 0.f};
    int swz = q * 8 + 8 * cid;
#pragma unroll
    for (int ks = 0; ks < KT / 32; ++ks) {
        int kk = ks * 32;
        const ushortT* abase = (kk < KH) ? Am : Ah;
        int kc = (kk < KH) ? kk : kk - KH;
        short8 a0 = *(const short8*)(abase + (size_t)r0c * KH + kc + q * 8);
        short8 a1 = *(const short8*)(abase + (size_t)r1c * KH + kc + q * 8);
#pragma unroll
        for (int j = 0; j < 8; ++j) {
            int col = j * 16 + cid;
            int p = (kk + swz + j * 128) & (KT - 1);
            short8 b = *(const short8*)(sW + col * KT + p);
            acc[0][j] = __builtin_amdgcn_mfma_f32_16x16x32_bf16(a0, b, acc[0][j], 0, 0, 0);
            acc[1][j] = __builtin_amdgcn_mfma_f32_16x16x32_bf16(a1, b, acc[1][j], 0, 0, 0);
        }
    }
    float bo[8];
#pragma unroll
    for (int j = 0; j < 8; ++j) bo[j] = bias[j * 16 + cid];
#pragma unroll
    for (int i = 0; i < 2; ++i) {
#pragma unroll
        for (int rr = 0; rr < 4; ++rr) {
            int row = rbase + i * 16 + q * 4 + rr;
            if (row < n) {
#pragma unroll
                for (int j = 0; j < 8; ++j) {
                    int col = j * 16 + cid;
                    float v = fmaxf(acc[i][j][rr] + bo[j], 0.f);
                    if (OUT_BF16) outbf[(size_t)row * 128 + col] = f32_to_bf16_rne(v);
                    else          outf[(size_t)row * 128 + col] = v;
                }
            }
        }
    }
}

// ---------------- fused head ----------------

__launch_bounds__(256)
__global__ void head_fused(const float* __restrict__ h3, const float* __restrict__ Wfc,
                           const float* __restrict__ bfc, const float* __restrict__ Wa1,
                           const float* __restrict__ ba1, const float* __restrict__ Wa2,
                           const float* __restrict__ ba2, const float* __restrict__ Wao,
                           const float* __restrict__ bao, float* __restrict__ fin, int n) {
    __shared__ float sH[32 * 128];
    __shared__ float sD1[32], sD3[32];
    __shared__ float sRed[2 * 32];
    int b = blockIdx.x, t = threadIdx.x;
    int base = b * 32;
    int rows = min(32, n - base);
    const float4* H4 = (const float4*)(h3 + (size_t)base * 128);
    int nv = rows * 32;
    for (int j = t; j < nv; j += 256) ((float4*)sH)[j] = H4[j];
    __syncthreads();
    {
        int node = t >> 3, seg = t & 7;
        const float* hrow = sH + node * 128 + seg * 16;
        float p1 = 0.f, p3 = 0.f;
#pragma unroll
        for (int q = 0; q < 16; q++) {
            int k = seg * 16 + q;
            float hv = hrow[q];
            p1 += hv * Wfc[k * 3 + 0];
            p3 += hv * Wfc[k * 3 + 2];
        }
        for (int m = 1; m < 8; m <<= 1) {
            p1 += __shfl_xor(p1, m, 64);
            p3 += __shfl_xor(p3, m, 64);
        }
        if ((t & 7) == 0) {
            sD1[node] = p1 + bfc[0];
            sD3[node] = p3 + bfc[2];
        }
    }
    __syncthreads();
    for (int j = t; j < 32 * 128; j += 256) {
        int node = j >> 7, k = j & 127;
        float a1 = sD1[node] * Wa1[k] + sD3[node] * Wa1[128 + k] + ba1[k];
        sH[j] = fmaxf(a1, 0.f);
    }
    __syncthreads();
    int o = t & 127, r = t >> 7;
    float b2 = ba2[o];
    float acc[16];
#pragma unroll
    for (int m = 0; m < 16; m++) acc[m] = b2;
    for (int kk = 0; kk < 32; ++kk) {
        float w[4];
#pragma unroll
        for (int q = 0; q < 4; q++) w[q] = Wa2[(4 * kk + q) * 128 + o];
#pragma unroll
        for (int m = 0; m < 16; m++) {
            float4 av = ((const float4*)sH)[(r * 16 + m) * 32 + kk];
            acc[m] += av.x * w[0] + av.y * w[1] + av.z * w[2] + av.w * w[3];
        }
    }
    float wao = Wao[o];
    float v[16];
#pragma unroll
    for (int m = 0; m < 16; m++) {
        v[m] = fmaxf(acc[m], 0.f) * wao;
        for (int s = 1; s < 64; s <<= 1) v[m] += __shfl_xor(v[m], s, 64);
    }
    int wave = t >> 6;
    int half = wave & 1;
    int lane = t & 63;
    if (lane == 0) {
#pragma unroll
        for (int m = 0; m < 16; m++) sRed[half * 32 + r * 16 + m] = v[m];
    }
    __syncthreads();
    if (t < rows) {
        float aux = sRed[t] + sRed[32 + t] + bao[0];
        fin[(size_t)(base + t) * 3 + 0] = sD1[t];
        fin[(size_t)(base + t) * 3 + 1] = aux;
        fin[(size_t)(base + t) * 3 + 2] = sD3[t];
    }
}

// ---------------- per-graph mean pool ----------------

__global__ void pool_kernel(const float* __restrict__ fin, const int* __restrict__ batch,
                            float* __restrict__ out, int n) {
    int g = blockIdx.x, t = threadIdx.x;
    int lo = 0, hi = n;
    while (lo < hi) { int mid = (lo + hi) >> 1; if (batch[mid] < g) lo = mid + 1; else hi = mid; }
    int start = lo;
    lo = 0; hi = n;
    while (lo < hi) { int mid = (lo + hi) >> 1; if (batch[mid] < g + 1) lo = mid + 1; else hi = mid; }
    int end = lo;
    float s0 = 0.f, s1 = 0.f, s2 = 0.f;
    for (int i = start + t; i < end; i += 256) {
        s0 += fin[(size_t)i * 3 + 0];
        s1 += fin[(size_t)i * 3 + 1];
        s2 += fin[(size_t)i * 3 + 2];
    }
    __shared__ float r0[256], r1[256], r2[256];
    r0[t] = s0; r1[t] = s1; r2[t] = s2;
    __syncthreads();
    for (int off = 128; off > 0; off >>= 1) {
        if (t < off) { r0[t] += r0[t + off]; r1[t] += r1[t + off]; r2[t] += r2[t + off]; }
        __syncthreads();
    }
    if (t == 0) {
        float c = (float)max(end - start, 1);
        out[g * 3 + 0] = r0[0] / c;
        out[g * 3 + 1] = r1[0] / c;
        out[g * 3 + 2] = r2[0] / c;
    }
}

// ---------------- launch ----------------

extern "C" void kernel_launch(void* const* d_in, const int* in_sizes, int n_in,
                              void* d_out, int out_size, void* d_ws, size_t ws_size,
                              hipStream_t stream) {
    const float* x    = (const float*)d_in[0];
    const int*   ei   = (const int*)d_in[1];
    const int*   batch= (const int*)d_in[2];
    const float* Wl0  = (const float*)d_in[3];
    const float* bl0  = (const float*)d_in[4];
    const float* Wr0  = (const float*)d_in[5];
    const float* Wl1  = (const float*)d_in[6];
    const float* bl1  = (const float*)d_in[7];
    const float* Wr1  = (const float*)d_in[8];
    const float* Wl2  = (const float*)d_in[9];
    const float* bl2  = (const float*)d_in[10];
    const float* Wr2  = (const float*)d_in[11];
    const float* Wfc  = (const float*)d_in[12];
    const float* bfc  = (const float*)d_in[13];
    const float* Wa1  = (const float*)d_in[14];
    const float* ba1  = (const float*)d_in[15];
    const float* Wa2  = (const float*)d_in[16];
    const float* ba2  = (const float*)d_in[17];
    const float* Wao  = (const float*)d_in[18];
    const float* bao  = (const float*)d_in[19];

    const int N = in_sizes[0] / 32;
    const int E = in_sizes[1] / 2;
    const int G = out_size / 3;
    const int* src = ei;
    const int* dst = ei + E;
    float* out = (float*)d_out;
    const int NB = (N + NR - 1) / NR;

    char* p = (char*)d_ws;
    auto carve = [&](size_t bytes) {
        void* r = (void*)p;
        p += (bytes + 255) & ~(size_t)255;
        return r;
    };
    int*      bcnt     = (int*)carve((size_t)NB * 4);
    int*      bstart   = (int*)carve((size_t)(NB + 1) * 4);
    int*      gcur     = (int*)carve((size_t)NB * 4);
    int*      row_start= (int*)carve((size_t)(N + 1) * 4);
    unsigned* packed   = (unsigned*)carve((size_t)E * 4);
    int*      srcs     = (int*)carve((size_t)E * 4);
    ushortT*  aggbf    = (ushortT*)carve((size_t)N * 128 * 2);
    float*    h3f      = (float*)carve((size_t)N * 128 * 4);
    ushortT*  xbf      = (ushortT*)carve((size_t)N * 32 * 2);
    ushortT*  hbf0     = (ushortT*)carve((size_t)N * 128 * 2);
    ushortT*  hbf1     = (ushortT*)carve((size_t)N * 128 * 2);
    float*    fin      = (float*)carve((size_t)N * 3 * 4);
    ushortT*  Wt0      = (ushortT*)carve((size_t)128 * 64 * 2);
    ushortT*  Wt1      = (ushortT*)carve((size_t)128 * 256 * 2);
    ushortT*  Wt2      = (ushortT*)carve((size_t)128 * 256 * 2);

    const int gemm_grid = (N + 127) / 128;
    const int part_grid = (E + PART_CH - 1) / PART_CH;

    // x -> bf16 ; weight prep
    to_bf16_vec<<<(N * 32 / 4 + 255) / 256, 256, 0, stream>>>(x, xbf, N * 32 / 4);
    prep_wt<<<(128 * 64 + 255) / 256, 256, 0, stream>>>(Wl0, Wr0, Wt0, 32);
    prep_wt<<<(128 * 256 + 255) / 256, 256, 0, stream>>>(Wl1, Wr1, Wt1, 128);
    prep_wt<<<(128 * 256 + 255) / 256, 256, 0, stream>>>(Wl2, Wr2, Wt2, 128);

    // CSR build (bucketed counting sort)
    hipMemsetAsync(bcnt, 0, (size_t)NB * 4, stream);
    bucket_count<<<part_grid, 256, 0, stream>>>(dst, bcnt, E, NB);
    bucket_scan<<<1, 256, 0, stream>>>(bcnt, bstart, gcur, NB, E);
    partition_edges<<<part_grid, 256, 0, stream>>>(src, dst, gcur, packed, E, NB);
    bucket_sort<<<NB, 256, 0, stream>>>(packed, bstart, row_start, srcs, N);

    // layer 0 (KH=32)
    aggregate_mean_bf16<4><<<(N * 2 + 255) / 256, 256, 0, stream>>>(
        (const uint4*)xbf, aggbf, srcs, row_start, N);
    gemm_mfma<32, true><<<gemm_grid, 256, 0, stream>>>(
        aggbf, xbf, Wt0, bl0, (float*)nullptr, hbf0, N);
    // layer 1 (KH=128)
    aggregate_mean_bf16<16><<<(N * 8 + 255) / 256, 256, 0, stream>>>(
        (const uint4*)hbf0, aggbf, srcs, row_start, N);
    gemm_mfma<128, true><<<gemm_grid, 256, 0, stream>>>(
        aggbf, hbf0, Wt1, bl1, (float*)nullptr, hbf1, N);
    // layer 2 (KH=128): f32 out for the head
    aggregate_mean_bf16<16><<<(N * 8 + 255) / 256, 256, 0, stream>>>(
        (const uint4*)hbf1, aggbf, srcs, row_start, N);
    gemm_mfma<128, false><<<gemm_grid, 256, 0, stream>>>(
        aggbf, hbf1, Wt2, bl2, h3f, (ushortT*)nullptr, N);

    // fused head -> fin
    head_fused<<<(N + 31) / 32, 256, 0, stream>>>(
        h3f, Wfc, bfc, Wa1, ba1, Wa2, ba2, Wao, bao, fin, N);

    // per-graph mean pool
    pool_kernel<<<G, 256, 0, stream>>>(fin, batch, out, N);
}

// Round 5
// 444.563 us; speedup vs baseline: 3.1763x; 1.0687x over previous
//
#include <hip/hip_runtime.h>

#define NR 128        // dst nodes per bucket
#define PART_CH 4096  // edges per partition/count block
typedef unsigned short ushortT;
typedef __attribute__((ext_vector_type(8))) short short8;
typedef __attribute__((ext_vector_type(4))) float float4v;

__device__ __forceinline__ unsigned short f32_to_bf16_rne(float f) {
    unsigned u = __float_as_uint(f);
    unsigned r = (u + 0x7fffu + ((u >> 16) & 1u)) >> 16;
    return (unsigned short)r;
}

__device__ __forceinline__ void accum8(float* acc, uint4 v) {
    unsigned u[4] = {v.x, v.y, v.z, v.w};
#pragma unroll
    for (int q = 0; q < 4; q++) {
        acc[2 * q]     += __uint_as_float(u[q] << 16);
        acc[2 * q + 1] += __uint_as_float(u[q] & 0xffff0000u);
    }
}

// ---------------- CSR build: bucketed counting sort ----------------

__launch_bounds__(256)
__global__ void bucket_count(const int* __restrict__ dst, int* __restrict__ bcnt, int E, int NB) {
    __shared__ int h[1024];
    int t = threadIdx.x;
    for (int j = t; j < NB; j += 256) h[j] = 0;
    __syncthreads();
    int e0 = blockIdx.x * PART_CH;
    int e1 = min(e0 + PART_CH, E);
    for (int e = e0 + t; e < e1; e += 256) atomicAdd(&h[dst[e] >> 7], 1);
    __syncthreads();
    for (int j = t; j < NB; j += 256) {
        int v = h[j];
        if (v) atomicAdd(&bcnt[j], v);
    }
}

__launch_bounds__(256)
__global__ void bucket_scan(const int* __restrict__ bcnt, int* __restrict__ bstart,
                            int* __restrict__ gcur, int NB, int E) {
    __shared__ int sh[256];
    int t = threadIdx.x;
    int v[4];
    int tot = 0;
#pragma unroll
    for (int j = 0; j < 4; j++) {
        int idx = t * 4 + j;
        v[j] = (idx < NB) ? bcnt[idx] : 0;
        tot += v[j];
    }
    sh[t] = tot;
    __syncthreads();
    for (int off = 1; off < 256; off <<= 1) {
        int add = (t >= off) ? sh[t - off] : 0;
        __syncthreads();
        sh[t] += add;
        __syncthreads();
    }
    int run = sh[t] - tot;
#pragma unroll
    for (int j = 0; j < 4; j++) {
        int idx = t * 4 + j;
        if (idx < NB) { bstart[idx] = run; gcur[idx] = run; }
        run += v[j];
    }
    if (t == 0) bstart[NB] = E;
}

// partition edges into buckets; packed record = src | (dst&127)<<17  (src < 2^17)
__launch_bounds__(256)
__global__ void partition_edges(const int* __restrict__ src, const int* __restrict__ dst,
                                int* __restrict__ gcur, unsigned* __restrict__ packed,
                                int E, int NB) {
    __shared__ int hist[1024];
    __shared__ int base[1024];
    int t = threadIdx.x;
    int e0 = blockIdx.x * PART_CH;
    int e1 = min(e0 + PART_CH, E);
    for (int j = t; j < NB; j += 256) hist[j] = 0;
    __syncthreads();
    for (int e = e0 + t; e < e1; e += 256) atomicAdd(&hist[dst[e] >> 7], 1);
    __syncthreads();
    for (int j = t; j < NB; j += 256) {
        int h = hist[j];
        base[j] = h ? atomicAdd(&gcur[j], h) : 0;
    }
    __syncthreads();
    for (int j = t; j < NB; j += 256) hist[j] = base[j];
    __syncthreads();
    for (int e = e0 + t; e < e1; e += 256) {
        int d = dst[e];
        int b = d >> 7;
        int pos = atomicAdd(&hist[b], 1);
        packed[pos] = (unsigned)src[e] | ((unsigned)(d & (NR - 1)) << 17);
    }
}

__launch_bounds__(256)
__global__ void bucket_sort(const unsigned* __restrict__ packed, const int* __restrict__ bstart,
                            int* __restrict__ row_start, int* __restrict__ srcs, int N) {
    __shared__ int cnt[NR];
    __shared__ int sc[NR];
    __shared__ int cur[NR];
    int b = blockIdx.x, t = threadIdx.x;
    int nb0 = b * NR;
    int nnode = min(NR, N - nb0);
    int lo = bstart[b], hi = bstart[b + 1];
    if (t < NR) cnt[t] = 0;
    __syncthreads();
    for (int j = lo + t; j < hi; j += 256) atomicAdd(&cnt[packed[j] >> 17], 1);
    __syncthreads();
    if (t < NR) sc[t] = cnt[t];
    __syncthreads();
    for (int off = 1; off < NR; off <<= 1) {
        int add = (t >= off && t < NR) ? sc[t - off] : 0;
        __syncthreads();
        if (t < NR) sc[t] += add;
        __syncthreads();
    }
    if (t < nnode) {
        int s = lo + sc[t] - cnt[t];
        row_start[nb0 + t] = s;
        cur[t] = s;
    }
    if (t == 0 && nb0 + nnode == N) row_start[N] = hi;
    __syncthreads();
    for (int j = lo + t; j < hi; j += 256) {
        unsigned pk = packed[j];
        int pos = atomicAdd(&cur[pk >> 17], 1);
        srcs[pos] = (int)(pk & 0x1FFFFu);
    }
}

// ---------------- f32 -> bf16 ----------------

__global__ void to_bf16_vec(const float* __restrict__ in, ushortT* __restrict__ out, int n4) {
    int t = blockIdx.x * 256 + threadIdx.x;
    if (t < n4) {
        float4 v = ((const float4*)in)[t];
        ushort4 o;
        o.x = f32_to_bf16_rne(v.x);
        o.y = f32_to_bf16_rne(v.y);
        o.z = f32_to_bf16_rne(v.z);
        o.w = f32_to_bf16_rne(v.w);
        ((ushort4*)out)[t] = o;
    }
}

// ---------------- weight prep ----------------

__global__ void prep_wt(const float* __restrict__ Wl, const float* __restrict__ Wr,
                        ushortT* __restrict__ Wt, int KH) {
    int KT = 2 * KH;
    int tid = blockIdx.x * 256 + threadIdx.x;
    if (tid >= 128 * KT) return;
    int col = tid / KT, k = tid - col * KT;
    float v = (k < KH) ? Wl[k * 128 + col] : Wr[(k - KH) * 128 + col];
    int pos = (k + 8 * col) & (KT - 1);
    Wt[col * KT + pos] = f32_to_bf16_rne(v);
}

// single 128x128 weight, same swizzle
__global__ void prep_w1(const float* __restrict__ W, ushortT* __restrict__ Wt) {
    int tid = blockIdx.x * 256 + threadIdx.x;
    if (tid >= 128 * 128) return;
    int col = tid >> 7, k = tid & 127;
    int pos = (k + 8 * col) & 127;
    Wt[col * 128 + pos] = f32_to_bf16_rne(W[k * 128 + col]);
}

// ---------------- aggregation ----------------

template <int CPN>
__launch_bounds__(256)
__global__ void aggregate_mean_bf16(const uint4* __restrict__ hin, ushortT* __restrict__ out,
                                    const int* __restrict__ srcs, const int* __restrict__ rs, int n) {
    constexpr int TPN = CPN / 2;
    int tid = blockIdx.x * 256 + threadIdx.x;
    if (tid >= n * TPN) return;
    int i = tid / TPN;
    int c = tid & (TPN - 1);
    int lo = rs[i], hi = rs[i + 1];
    float acc0[8], acc1[8];
#pragma unroll
    for (int q = 0; q < 8; q++) { acc0[q] = 0.f; acc1[q] = 0.f; }
    int e = lo;
    for (; e + 4 <= hi; e += 4) {
        int s0 = srcs[e], s1 = srcs[e + 1], s2 = srcs[e + 2], s3 = srcs[e + 3];
        uint4 a0 = hin[(size_t)s0 * CPN + c];
        uint4 b0 = hin[(size_t)s0 * CPN + c + TPN];
        uint4 a1 = hin[(size_t)s1 * CPN + c];
        uint4 b1 = hin[(size_t)s1 * CPN + c + TPN];
        uint4 a2 = hin[(size_t)s2 * CPN + c];
        uint4 b2 = hin[(size_t)s2 * CPN + c + TPN];
        uint4 a3 = hin[(size_t)s3 * CPN + c];
        uint4 b3 = hin[(size_t)s3 * CPN + c + TPN];
        accum8(acc0, a0); accum8(acc1, b0);
        accum8(acc0, a1); accum8(acc1, b1);
        accum8(acc0, a2); accum8(acc1, b2);
        accum8(acc0, a3); accum8(acc1, b3);
    }
    for (; e < hi; ++e) {
        int s = srcs[e];
        accum8(acc0, hin[(size_t)s * CPN + c]);
        accum8(acc1, hin[(size_t)s * CPN + c + TPN]);
    }
    float inv = 1.0f / (float)max(hi - lo, 1);
    uint4 o0, o1;
    o0.x = (unsigned)f32_to_bf16_rne(acc0[0] * inv) | ((unsigned)f32_to_bf16_rne(acc0[1] * inv) << 16);
    o0.y = (unsigned)f32_to_bf16_rne(acc0[2] * inv) | ((unsigned)f32_to_bf16_rne(acc0[3] * inv) << 16);
    o0.z = (unsigned)f32_to_bf16_rne(acc0[4] * inv) | ((unsigned)f32_to_bf16_rne(acc0[5] * inv) << 16);
    o0.w = (unsigned)f32_to_bf16_rne(acc0[6] * inv) | ((unsigned)f32_to_bf16_rne(acc0[7] * inv) << 16);
    o1.x = (unsigned)f32_to_bf16_rne(acc1[0] * inv) | ((unsigned)f32_to_bf16_rne(acc1[1] * inv) << 16);
    o1.y = (unsigned)f32_to_bf16_rne(acc1[2] * inv) | ((unsigned)f32_to_bf16_rne(acc1[3] * inv) << 16);
    o1.z = (unsigned)f32_to_bf16_rne(acc1[4] * inv) | ((unsigned)f32_to_bf16_rne(acc1[5] * inv) << 16);
    o1.w = (unsigned)f32_to_bf16_rne(acc1[6] * inv) | ((unsigned)f32_to_bf16_rne(acc1[7] * inv) << 16);
    ((uint4*)out)[(size_t)i * CPN + c] = o0;
    ((uint4*)out)[(size_t)i * CPN + c + TPN] = o1;
}

// ---------------- MFMA GEMM: out = relu([Am | Ah] @ [Wl;Wr] + bias) --------------------

template <int KH, bool OUT_BF16>
__launch_bounds__(256, 2)
__global__ void gemm_mfma(const ushortT* __restrict__ Am, const ushortT* __restrict__ Ah,
                          const ushortT* __restrict__ Wt, const float* __restrict__ bias,
                          float* __restrict__ outf, ushortT* __restrict__ outbf, int n) {
    constexpr int KT = 2 * KH;
    __shared__ ushortT sW[128 * KT];
    int t = threadIdx.x;
    constexpr int TOT16 = 128 * KT * 2 / 16;
    {
        const uint4* Wg = (const uint4*)Wt;
        uint4* Ws = (uint4*)sW;
        for (int j = t; j < TOT16; j += 256) Ws[j] = Wg[j];
    }
    __syncthreads();
    int wv = t >> 6, lane = t & 63;
    int q = lane >> 4, cid = lane & 15;
    int rbase = blockIdx.x * 128 + wv * 32;
    int r0 = rbase + cid, r1 = r0 + 16;
    int r0c = min(r0, n - 1), r1c = min(r1, n - 1);
    float4v acc[2][8];
#pragma unroll
    for (int i = 0; i < 2; i++)
#pragma unroll
        for (int j = 0; j < 8; j++) acc[i][j] = (float4v){0.f, 0.f, 0.f, 0.f};
    int swz = q * 8 + 8 * cid;
#pragma unroll
    for (int ks = 0; ks < KT / 32; ++ks) {
        int kk = ks * 32;
        const ushortT* abase = (kk < KH) ? Am : Ah;
        int kc = (kk < KH) ? kk : kk - KH;
        short8 a0 = *(const short8*)(abase + (size_t)r0c * KH + kc + q * 8);
        short8 a1 = *(const short8*)(abase + (size_t)r1c * KH + kc + q * 8);
#pragma unroll
        for (int j = 0; j < 8; ++j) {
            int col = j * 16 + cid;
            int p = (kk + swz + j * 128) & (KT - 1);
            short8 b = *(const short8*)(sW + col * KT + p);
            acc[0][j] = __builtin_amdgcn_mfma_f32_16x16x32_bf16(a0, b, acc[0][j], 0, 0, 0);
            acc[1][j] = __builtin_amdgcn_mfma_f32_16x16x32_bf16(a1, b, acc[1][j], 0, 0, 0);
        }
    }
    float bo[8];
#pragma unroll
    for (int j = 0; j < 8; ++j) bo[j] = bias[j * 16 + cid];
#pragma unroll
    for (int i = 0; i < 2; ++i) {
#pragma unroll
        for (int rr = 0; rr < 4; ++rr) {
            int row = rbase + i * 16 + q * 4 + rr;
            if (row < n) {
#pragma unroll
                for (int j = 0; j < 8; ++j) {
                    int col = j * 16 + cid;
                    float v = fmaxf(acc[i][j][rr] + bo[j], 0.f);
                    if (OUT_BF16) outbf[(size_t)row * 128 + col] = f32_to_bf16_rne(v);
                    else          outf[(size_t)row * 128 + col] = v;
                }
            }
        }
    }
}

// ---- layer-2 variant: h3 never materialized; epilogue computes d1/d3 -> fin[:,0],fin[:,2]

template <int KH>
__launch_bounds__(256, 2)
__global__ void gemm_mfma_fin(const ushortT* __restrict__ Am, const ushortT* __restrict__ Ah,
                              const ushortT* __restrict__ Wt, const float* __restrict__ bias,
                              const float* __restrict__ Wfc, const float* __restrict__ bfc,
                              float* __restrict__ fin, int n) {
    constexpr int KT = 2 * KH;
    __shared__ ushortT sW[128 * KT];
    int t = threadIdx.x;
    constexpr int TOT16 = 128 * KT * 2 / 16;
    {
        const uint4* Wg = (const uint4*)Wt;
        uint4* Ws = (uint4*)sW;
        for (int j = t; j < TOT16; j += 256) Ws[j] = Wg[j];
    }
    __syncthreads();
    int wv = t >> 6, lane = t & 63;
    int q = lane >> 4, cid = lane & 15;
    int rbase = blockIdx.x * 128 + wv * 32;
    int r0 = rbase + cid, r1 = r0 + 16;
    int r0c = min(r0, n - 1), r1c = min(r1, n - 1);
    float4v acc[2][8];
#pragma unroll
    for (int i = 0; i < 2; i++)
#pragma unroll
        for (int j = 0; j < 8; j++) acc[i][j] = (float4v){0.f, 0.f, 0.f, 0.f};
    int swz = q * 8 + 8 * cid;
#pragma unroll
    for (int ks = 0; ks < KT / 32; ++ks) {
        int kk = ks * 32;
        const ushortT* abase = (kk < KH) ? Am : Ah;
        int kc = (kk < KH) ? kk : kk - KH;
        short8 a0 = *(const short8*)(abase + (size_t)r0c * KH + kc + q * 8);
        short8 a1 = *(const short8*)(abase + (size_t)r1c * KH + kc + q * 8);
#pragma unroll
        for (int j = 0; j < 8; ++j) {
            int col = j * 16 + cid;
            int p = (kk + swz + j * 128) & (KT - 1);
            short8 b = *(const short8*)(sW + col * KT + p);
            acc[0][j] = __builtin_amdgcn_mfma_f32_16x16x32_bf16(a0, b, acc[0][j], 0, 0, 0);
            acc[1][j] = __builtin_amdgcn_mfma_f32_16x16x32_bf16(a1, b, acc[1][j], 0, 0, 0);
        }
    }
    float bo[8], w1[8], w3[8];
#pragma unroll
    for (int j = 0; j < 8; ++j) {
        int col = j * 16 + cid;
        bo[j] = bias[col];
        w1[j] = Wfc[col * 3 + 0];
        w3[j] = Wfc[col * 3 + 2];
    }
    float bfc0 = bfc[0], bfc2 = bfc[2];
#pragma unroll
    for (int i = 0; i < 2; ++i) {
#pragma unroll
        for (int rr = 0; rr < 4; ++rr) {
            float p1 = 0.f, p3 = 0.f;
#pragma unroll
            for (int j = 0; j < 8; ++j) {
                float v = fmaxf(acc[i][j][rr] + bo[j], 0.f);
                p1 += v * w1[j];
                p3 += v * w3[j];
            }
            p1 += __shfl_xor(p1, 1, 64); p3 += __shfl_xor(p3, 1, 64);
            p1 += __shfl_xor(p1, 2, 64); p3 += __shfl_xor(p3, 2, 64);
            p1 += __shfl_xor(p1, 4, 64); p3 += __shfl_xor(p3, 4, 64);
            p1 += __shfl_xor(p1, 8, 64); p3 += __shfl_xor(p3, 8, 64);
            int row = rbase + i * 16 + q * 4 + rr;
            if (cid == 0 && row < n) {
                fin[(size_t)row * 3 + 0] = p1 + bfc0;
                fin[(size_t)row * 3 + 2] = p3 + bfc2;
            }
        }
    }
}

// ---------------- head: a1 build (LDS) + a2 MFMA + Wao reduce -> fin[:,1] --------------

__launch_bounds__(256, 2)
__global__ void head_mfma(const ushortT* __restrict__ Wa2t, const float* __restrict__ Wa1,
                          const float* __restrict__ ba1, const float* __restrict__ ba2,
                          const float* __restrict__ Wao, const float* __restrict__ bao,
                          float* __restrict__ fin, int n) {
    __shared__ ushortT sW[128 * 128];
    __shared__ ushortT sA[128 * 128];   // a1 tile, chunk-swizzled: chunk c of row r at c^(r&15)
    int t = threadIdx.x;
    {
        const uint4* Wg = (const uint4*)Wa2t;
        uint4* Ws = (uint4*)sW;
        for (int j = t; j < 128 * 128 * 2 / 16; j += 256) Ws[j] = Wg[j];
    }
    int rbase = blockIdx.x * 128;
#pragma unroll
    for (int it = 0; it < 8; ++it) {
        int idx = it * 256 + t;       // 128 nodes * 16 chunks
        int node = idx >> 4;
        int c = idx & 15;
        int row = min(rbase + node, n - 1);
        float d1 = fin[(size_t)row * 3 + 0];
        float d3 = fin[(size_t)row * 3 + 2];
        unsigned pk[4];
#pragma unroll
        for (int q = 0; q < 4; ++q) {
            int k = c * 8 + q * 2;
            float v0 = fmaxf(d1 * Wa1[k]     + d3 * Wa1[128 + k]     + ba1[k],     0.f);
            float v1 = fmaxf(d1 * Wa1[k + 1] + d3 * Wa1[128 + k + 1] + ba1[k + 1], 0.f);
            pk[q] = (unsigned)f32_to_bf16_rne(v0) | ((unsigned)f32_to_bf16_rne(v1) << 16);
        }
        int cs = c ^ (node & 15);
        *(uint4*)(sA + node * 128 + cs * 8) = make_uint4(pk[0], pk[1], pk[2], pk[3]);
    }
    __syncthreads();
    int wv = t >> 6, lane = t & 63;
    int q = lane >> 4, cid = lane & 15;
    int rl0 = wv * 32 + cid, rl1 = rl0 + 16;
    float4v acc[2][8];
#pragma unroll
    for (int i = 0; i < 2; i++)
#pragma unroll
        for (int j = 0; j < 8; j++) acc[i][j] = (float4v){0.f, 0.f, 0.f, 0.f};
    int swz = q * 8 + 8 * cid;
#pragma unroll
    for (int ks = 0; ks < 4; ++ks) {
        int kk = ks * 32;
        int ch = (ks * 4 + q) ^ cid;
        short8 a0 = *(const short8*)(sA + rl0 * 128 + ch * 8);
        short8 a1 = *(const short8*)(sA + rl1 * 128 + ch * 8);
#pragma unroll
        for (int j = 0; j < 8; ++j) {
            int p = (kk + swz) & 127;
            short8 b = *(const short8*)(sW + (j * 16 + cid) * 128 + p);
            acc[0][j] = __builtin_amdgcn_mfma_f32_16x16x32_bf16(a0, b, acc[0][j], 0, 0, 0);
            acc[1][j] = __builtin_amdgcn_mfma_f32_16x16x32_bf16(a1, b, acc[1][j], 0, 0, 0);
        }
    }
    float b2[8], wo[8];
#pragma unroll
    for (int j = 0; j < 8; ++j) {
        int col = j * 16 + cid;
        b2[j] = ba2[col];
        wo[j] = Wao[col];
    }
    float bao0 = bao[0];
#pragma unroll
    for (int i = 0; i < 2; ++i) {
#pragma unroll
        for (int rr = 0; rr < 4; ++rr) {
            float s = 0.f;
#pragma unroll
            for (int j = 0; j < 8; ++j) s += fmaxf(acc[i][j][rr] + b2[j], 0.f) * wo[j];
            s += __shfl_xor(s, 1, 64);
            s += __shfl_xor(s, 2, 64);
            s += __shfl_xor(s, 4, 64);
            s += __shfl_xor(s, 8, 64);
            int row = rbase + wv * 32 + i * 16 + q * 4 + rr;
            if (cid == 0 && row < n) fin[(size_t)row * 3 + 1] = s + bao0;
        }
    }
}

// ---------------- per-graph mean pool ----------------

__global__ void pool_kernel(const float* __restrict__ fin, const int* __restrict__ batch,
                            float* __restrict__ out, int n) {
    int g = blockIdx.x, t = threadIdx.x;
    int lo = 0, hi = n;
    while (lo < hi) { int mid = (lo + hi) >> 1; if (batch[mid] < g) lo = mid + 1; else hi = mid; }
    int start = lo;
    lo = 0; hi = n;
    while (lo < hi) { int mid = (lo + hi) >> 1; if (batch[mid] < g + 1) lo = mid + 1; else hi = mid; }
    int end = lo;
    float s0 = 0.f, s1 = 0.f, s2 = 0.f;
    for (int i = start + t; i < end; i += 256) {
        s0 += fin[(size_t)i * 3 + 0];
        s1 += fin[(size_t)i * 3 + 1];
        s2 += fin[(size_t)i * 3 + 2];
    }
    __shared__ float r0[256], r1[256], r2[256];
    r0[t] = s0; r1[t] = s1; r2[t] = s2;
    __syncthreads();
    for (int off = 128; off > 0; off >>= 1) {
        if (t < off) { r0[t] += r0[t + off]; r1[t] += r1[t + off]; r2[t] += r2[t + off]; }
        __syncthreads();
    }
    if (t == 0) {
        float c = (float)max(end - start, 1);
        out[g * 3 + 0] = r0[0] / c;
        out[g * 3 + 1] = r1[0] / c;
        out[g * 3 + 2] = r2[0] / c;
    }
}

// ---------------- launch ----------------

extern "C" void kernel_launch(void* const* d_in, const int* in_sizes, int n_in,
                              void* d_out, int out_size, void* d_ws, size_t ws_size,
                              hipStream_t stream) {
    const float* x    = (const float*)d_in[0];
    const int*   ei   = (const int*)d_in[1];
    const int*   batch= (const int*)d_in[2];
    const float* Wl0  = (const float*)d_in[3];
    const float* bl0  = (const float*)d_in[4];
    const float* Wr0  = (const float*)d_in[5];
    const float* Wl1  = (const float*)d_in[6];
    const float* bl1  = (const float*)d_in[7];
    const float* Wr1  = (const float*)d_in[8];
    const float* Wl2  = (const float*)d_in[9];
    const float* bl2  = (const float*)d_in[10];
    const float* Wr2  = (const float*)d_in[11];
    const float* Wfc  = (const float*)d_in[12];
    const float* bfc  = (const float*)d_in[13];
    const float* Wa1  = (const float*)d_in[14];
    const float* ba1  = (const float*)d_in[15];
    const float* Wa2  = (const float*)d_in[16];
    const float* ba2  = (const float*)d_in[17];
    const float* Wao  = (const float*)d_in[18];
    const float* bao  = (const float*)d_in[19];

    const int N = in_sizes[0] / 32;
    const int E = in_sizes[1] / 2;
    const int G = out_size / 3;
    const int* src = ei;
    const int* dst = ei + E;
    float* out = (float*)d_out;
    const int NB = (N + NR - 1) / NR;

    char* p = (char*)d_ws;
    auto carve = [&](size_t bytes) {
        void* r = (void*)p;
        p += (bytes + 255) & ~(size_t)255;
        return r;
    };
    int*      bcnt     = (int*)carve((size_t)NB * 4);
    int*      bstart   = (int*)carve((size_t)(NB + 1) * 4);
    int*      gcur     = (int*)carve((size_t)NB * 4);
    int*      row_start= (int*)carve((size_t)(N + 1) * 4);
    unsigned* packed   = (unsigned*)carve((size_t)E * 4);
    int*      srcs     = (int*)carve((size_t)E * 4);
    ushortT*  aggbf    = (ushortT*)carve((size_t)N * 128 * 2);
    ushortT*  xbf      = (ushortT*)carve((size_t)N * 32 * 2);
    ushortT*  hbf0     = (ushortT*)carve((size_t)N * 128 * 2);
    ushortT*  hbf1     = (ushortT*)carve((size_t)N * 128 * 2);
    float*    fin      = (float*)carve((size_t)N * 3 * 4);
    ushortT*  Wt0      = (ushortT*)carve((size_t)128 * 64 * 2);
    ushortT*  Wt1      = (ushortT*)carve((size_t)128 * 256 * 2);
    ushortT*  Wt2      = (ushortT*)carve((size_t)128 * 256 * 2);
    ushortT*  Wa2t     = (ushortT*)carve((size_t)128 * 128 * 2);

    const int gemm_grid = (N + 127) / 128;
    const int part_grid = (E + PART_CH - 1) / PART_CH;

    // x -> bf16 ; weight prep
    to_bf16_vec<<<(N * 32 / 4 + 255) / 256, 256, 0, stream>>>(x, xbf, N * 32 / 4);
    prep_wt<<<(128 * 64 + 255) / 256, 256, 0, stream>>>(Wl0, Wr0, Wt0, 32);
    prep_wt<<<(128 * 256 + 255) / 256, 256, 0, stream>>>(Wl1, Wr1, Wt1, 128);
    prep_wt<<<(128 * 256 + 255) / 256, 256, 0, stream>>>(Wl2, Wr2, Wt2, 128);
    prep_w1<<<(128 * 128 + 255) / 256, 256, 0, stream>>>(Wa2, Wa2t);

    // CSR build (bucketed counting sort)
    hipMemsetAsync(bcnt, 0, (size_t)NB * 4, stream);
    bucket_count<<<part_grid, 256, 0, stream>>>(dst, bcnt, E, NB);
    bucket_scan<<<1, 256, 0, stream>>>(bcnt, bstart, gcur, NB, E);
    partition_edges<<<part_grid, 256, 0, stream>>>(src, dst, gcur, packed, E, NB);
    bucket_sort<<<NB, 256, 0, stream>>>(packed, bstart, row_start, srcs, N);

    // layer 0 (KH=32)
    aggregate_mean_bf16<4><<<(N * 2 + 255) / 256, 256, 0, stream>>>(
        (const uint4*)xbf, aggbf, srcs, row_start, N);
    gemm_mfma<32, true><<<gemm_grid, 256, 0, stream>>>(
        aggbf, xbf, Wt0, bl0, (float*)nullptr, hbf0, N);
    // layer 1 (KH=128)
    aggregate_mean_bf16<16><<<(N * 8 + 255) / 256, 256, 0, stream>>>(
        (const uint4*)hbf0, aggbf, srcs, row_start, N);
    gemm_mfma<128, true><<<gemm_grid, 256, 0, stream>>>(
        aggbf, hbf0, Wt1, bl1, (float*)nullptr, hbf1, N);
    // layer 2 (KH=128): fused d1/d3 epilogue -> fin[:,0], fin[:,2]
    aggregate_mean_bf16<16><<<(N * 8 + 255) / 256, 256, 0, stream>>>(
        (const uint4*)hbf1, aggbf, srcs, row_start, N);
    gemm_mfma_fin<128><<<gemm_grid, 256, 0, stream>>>(
        aggbf, hbf1, Wt2, bl2, Wfc, bfc, fin, N);

    // head aux MLP (MFMA) -> fin[:,1]
    head_mfma<<<gemm_grid, 256, 0, stream>>>(
        Wa2t, Wa1, ba1, ba2, Wao, bao, fin, N);

    // per-graph mean pool
    pool_kernel<<<G, 256, 0, stream>>>(fin, batch, out, N);
}

// Round 6
// 396.174 us; speedup vs baseline: 3.5642x; 1.1221x over previous
//
#include <hip/hip_runtime.h>

#define NR 128        // dst nodes per bucket
#define PART_CH 4096  // edges per partition/count block
typedef unsigned short ushortT;
typedef __attribute__((ext_vector_type(8))) short short8;
typedef __attribute__((ext_vector_type(4))) float float4v;

__device__ __forceinline__ unsigned short f32_to_bf16_rne(float f) {
    unsigned u = __float_as_uint(f);
    unsigned r = (u + 0x7fffu + ((u >> 16) & 1u)) >> 16;
    return (unsigned short)r;
}

__device__ __forceinline__ void accum8(float* acc, uint4 v) {
    unsigned u[4] = {v.x, v.y, v.z, v.w};
#pragma unroll
    for (int q = 0; q < 4; q++) {
        acc[2 * q]     += __uint_as_float(u[q] << 16);
        acc[2 * q + 1] += __uint_as_float(u[q] & 0xffff0000u);
    }
}

// ---------------- CSR build: bucketed counting sort ----------------

__launch_bounds__(256)
__global__ void bucket_count(const int* __restrict__ dst, int* __restrict__ bcnt, int E, int NB) {
    __shared__ int h[1024];
    int t = threadIdx.x;
    for (int j = t; j < NB; j += 256) h[j] = 0;
    __syncthreads();
    int e0 = blockIdx.x * PART_CH;
    int e1 = min(e0 + PART_CH, E);
    for (int e = e0 + t; e < e1; e += 256) atomicAdd(&h[dst[e] >> 7], 1);
    __syncthreads();
    for (int j = t; j < NB; j += 256) {
        int v = h[j];
        if (v) atomicAdd(&bcnt[j], v);
    }
}

__launch_bounds__(256)
__global__ void bucket_scan(const int* __restrict__ bcnt, int* __restrict__ bstart,
                            int* __restrict__ gcur, int NB, int E) {
    __shared__ int sh[256];
    int t = threadIdx.x;
    int v[4];
    int tot = 0;
#pragma unroll
    for (int j = 0; j < 4; j++) {
        int idx = t * 4 + j;
        v[j] = (idx < NB) ? bcnt[idx] : 0;
        tot += v[j];
    }
    sh[t] = tot;
    __syncthreads();
    for (int off = 1; off < 256; off <<= 1) {
        int add = (t >= off) ? sh[t - off] : 0;
        __syncthreads();
        sh[t] += add;
        __syncthreads();
    }
    int run = sh[t] - tot;
#pragma unroll
    for (int j = 0; j < 4; j++) {
        int idx = t * 4 + j;
        if (idx < NB) { bstart[idx] = run; gcur[idx] = run; }
        run += v[j];
    }
    if (t == 0) bstart[NB] = E;
}

// partition edges into buckets; packed record = src | (dst&127)<<17  (src < 2^17)
__launch_bounds__(256)
__global__ void partition_edges(const int* __restrict__ src, const int* __restrict__ dst,
                                int* __restrict__ gcur, unsigned* __restrict__ packed,
                                int E, int NB) {
    __shared__ int hist[1024];
    __shared__ int base[1024];
    int t = threadIdx.x;
    int e0 = blockIdx.x * PART_CH;
    int e1 = min(e0 + PART_CH, E);
    for (int j = t; j < NB; j += 256) hist[j] = 0;
    __syncthreads();
    for (int e = e0 + t; e < e1; e += 256) atomicAdd(&hist[dst[e] >> 7], 1);
    __syncthreads();
    for (int j = t; j < NB; j += 256) {
        int h = hist[j];
        base[j] = h ? atomicAdd(&gcur[j], h) : 0;
    }
    __syncthreads();
    for (int j = t; j < NB; j += 256) hist[j] = base[j];
    __syncthreads();
    for (int e = e0 + t; e < e1; e += 256) {
        int d = dst[e];
        int b = d >> 7;
        int pos = atomicAdd(&hist[b], 1);
        packed[pos] = (unsigned)src[e] | ((unsigned)(d & (NR - 1)) << 17);
    }
}

__launch_bounds__(256)
__global__ void bucket_sort(const unsigned* __restrict__ packed, const int* __restrict__ bstart,
                            int* __restrict__ row_start, int* __restrict__ srcs, int N) {
    __shared__ int cnt[NR];
    __shared__ int sc[NR];
    __shared__ int cur[NR];
    int b = blockIdx.x, t = threadIdx.x;
    int nb0 = b * NR;
    int nnode = min(NR, N - nb0);
    int lo = bstart[b], hi = bstart[b + 1];
    if (t < NR) cnt[t] = 0;
    __syncthreads();
    for (int j = lo + t; j < hi; j += 256) atomicAdd(&cnt[packed[j] >> 17], 1);
    __syncthreads();
    if (t < NR) sc[t] = cnt[t];
    __syncthreads();
    for (int off = 1; off < NR; off <<= 1) {
        int add = (t >= off && t < NR) ? sc[t - off] : 0;
        __syncthreads();
        if (t < NR) sc[t] += add;
        __syncthreads();
    }
    if (t < nnode) {
        int s = lo + sc[t] - cnt[t];
        row_start[nb0 + t] = s;
        cur[t] = s;
    }
    if (t == 0 && nb0 + nnode == N) row_start[N] = hi;
    __syncthreads();
    for (int j = lo + t; j < hi; j += 256) {
        unsigned pk = packed[j];
        int pos = atomicAdd(&cur[pk >> 17], 1);
        srcs[pos] = (int)(pk & 0x1FFFFu);
    }
}

// ---------------- f32 -> bf16 ----------------

__global__ void to_bf16_vec(const float* __restrict__ in, ushortT* __restrict__ out, int n4) {
    int t = blockIdx.x * 256 + threadIdx.x;
    if (t < n4) {
        float4 v = ((const float4*)in)[t];
        ushort4 o;
        o.x = f32_to_bf16_rne(v.x);
        o.y = f32_to_bf16_rne(v.y);
        o.z = f32_to_bf16_rne(v.z);
        o.w = f32_to_bf16_rne(v.w);
        ((ushort4*)out)[t] = o;
    }
}

// ---------------- weight prep ----------------

__global__ void prep_wt(const float* __restrict__ Wl, const float* __restrict__ Wr,
                        ushortT* __restrict__ Wt, int KH) {
    int KT = 2 * KH;
    int tid = blockIdx.x * 256 + threadIdx.x;
    if (tid >= 128 * KT) return;
    int col = tid / KT, k = tid - col * KT;
    float v = (k < KH) ? Wl[k * 128 + col] : Wr[(k - KH) * 128 + col];
    int pos = (k + 8 * col) & (KT - 1);
    Wt[col * KT + pos] = f32_to_bf16_rne(v);
}

// single 128x128 weight, same swizzle
__global__ void prep_w1(const float* __restrict__ W, ushortT* __restrict__ Wt) {
    int tid = blockIdx.x * 256 + threadIdx.x;
    if (tid >= 128 * 128) return;
    int col = tid >> 7, k = tid & 127;
    int pos = (k + 8 * col) & 127;
    Wt[col * 128 + pos] = f32_to_bf16_rne(W[k * 128 + col]);
}

// ---------------- aggregation ----------------

template <int CPN>
__launch_bounds__(256)
__global__ void aggregate_mean_bf16(const uint4* __restrict__ hin, ushortT* __restrict__ out,
                                    const int* __restrict__ srcs, const int* __restrict__ rs, int n) {
    constexpr int TPN = CPN / 2;
    int tid = blockIdx.x * 256 + threadIdx.x;
    if (tid >= n * TPN) return;
    int i = tid / TPN;
    int c = tid & (TPN - 1);
    int lo = rs[i], hi = rs[i + 1];
    float acc0[8], acc1[8];
#pragma unroll
    for (int q = 0; q < 8; q++) { acc0[q] = 0.f; acc1[q] = 0.f; }
    int e = lo;
    for (; e + 4 <= hi; e += 4) {
        int s0 = srcs[e], s1 = srcs[e + 1], s2 = srcs[e + 2], s3 = srcs[e + 3];
        uint4 a0 = hin[(size_t)s0 * CPN + c];
        uint4 b0 = hin[(size_t)s0 * CPN + c + TPN];
        uint4 a1 = hin[(size_t)s1 * CPN + c];
        uint4 b1 = hin[(size_t)s1 * CPN + c + TPN];
        uint4 a2 = hin[(size_t)s2 * CPN + c];
        uint4 b2 = hin[(size_t)s2 * CPN + c + TPN];
        uint4 a3 = hin[(size_t)s3 * CPN + c];
        uint4 b3 = hin[(size_t)s3 * CPN + c + TPN];
        accum8(acc0, a0); accum8(acc1, b0);
        accum8(acc0, a1); accum8(acc1, b1);
        accum8(acc0, a2); accum8(acc1, b2);
        accum8(acc0, a3); accum8(acc1, b3);
    }
    for (; e < hi; ++e) {
        int s = srcs[e];
        accum8(acc0, hin[(size_t)s * CPN + c]);
        accum8(acc1, hin[(size_t)s * CPN + c + TPN]);
    }
    float inv = 1.0f / (float)max(hi - lo, 1);
    uint4 o0, o1;
    o0.x = (unsigned)f32_to_bf16_rne(acc0[0] * inv) | ((unsigned)f32_to_bf16_rne(acc0[1] * inv) << 16);
    o0.y = (unsigned)f32_to_bf16_rne(acc0[2] * inv) | ((unsigned)f32_to_bf16_rne(acc0[3] * inv) << 16);
    o0.z = (unsigned)f32_to_bf16_rne(acc0[4] * inv) | ((unsigned)f32_to_bf16_rne(acc0[5] * inv) << 16);
    o0.w = (unsigned)f32_to_bf16_rne(acc0[6] * inv) | ((unsigned)f32_to_bf16_rne(acc0[7] * inv) << 16);
    o1.x = (unsigned)f32_to_bf16_rne(acc1[0] * inv) | ((unsigned)f32_to_bf16_rne(acc1[1] * inv) << 16);
    o1.y = (unsigned)f32_to_bf16_rne(acc1[2] * inv) | ((unsigned)f32_to_bf16_rne(acc1[3] * inv) << 16);
    o1.z = (unsigned)f32_to_bf16_rne(acc1[4] * inv) | ((unsigned)f32_to_bf16_rne(acc1[5] * inv) << 16);
    o1.w = (unsigned)f32_to_bf16_rne(acc1[6] * inv) | ((unsigned)f32_to_bf16_rne(acc1[7] * inv) << 16);
    ((uint4*)out)[(size_t)i * CPN + c] = o0;
    ((uint4*)out)[(size_t)i * CPN + c + TPN] = o1;
}

// ---------------- MFMA GEMM: out = relu([Am | Ah] @ [Wl;Wr] + bias) --------------------

template <int KH, bool OUT_BF16>
__launch_bounds__(256, 2)
__global__ void gemm_mfma(const ushortT* __restrict__ Am, const ushortT* __restrict__ Ah,
                          const ushortT* __restrict__ Wt, const float* __restrict__ bias,
                          float* __restrict__ outf, ushortT* __restrict__ outbf, int n) {
    constexpr int KT = 2 * KH;
    __shared__ ushortT sW[128 * KT];
    int t = threadIdx.x;
    constexpr int TOT16 = 128 * KT * 2 / 16;
    {
        const uint4* Wg = (const uint4*)Wt;
        uint4* Ws = (uint4*)sW;
        for (int j = t; j < TOT16; j += 256) Ws[j] = Wg[j];
    }
    __syncthreads();
    int wv = t >> 6, lane = t & 63;
    int q = lane >> 4, cid = lane & 15;
    int rbase = blockIdx.x * 128 + wv * 32;
    int r0 = rbase + cid, r1 = r0 + 16;
    int r0c = min(r0, n - 1), r1c = min(r1, n - 1);
    float4v acc[2][8];
#pragma unroll
    for (int i = 0; i < 2; i++)
#pragma unroll
        for (int j = 0; j < 8; j++) acc[i][j] = (float4v){0.f, 0.f, 0.f, 0.f};
    int swz = q * 8 + 8 * cid;
#pragma unroll
    for (int ks = 0; ks < KT / 32; ++ks) {
        int kk = ks * 32;
        const ushortT* abase = (kk < KH) ? Am : Ah;
        int kc = (kk < KH) ? kk : kk - KH;
        short8 a0 = *(const short8*)(abase + (size_t)r0c * KH + kc + q * 8);
        short8 a1 = *(const short8*)(abase + (size_t)r1c * KH + kc + q * 8);
#pragma unroll
        for (int j = 0; j < 8; ++j) {
            int col = j * 16 + cid;
            int p = (kk + swz + j * 128) & (KT - 1);
            short8 b = *(const short8*)(sW + col * KT + p);
            acc[0][j] = __builtin_amdgcn_mfma_f32_16x16x32_bf16(a0, b, acc[0][j], 0, 0, 0);
            acc[1][j] = __builtin_amdgcn_mfma_f32_16x16x32_bf16(a1, b, acc[1][j], 0, 0, 0);
        }
    }
    float bo[8];
#pragma unroll
    for (int j = 0; j < 8; ++j) bo[j] = bias[j * 16 + cid];
#pragma unroll
    for (int i = 0; i < 2; ++i) {
#pragma unroll
        for (int rr = 0; rr < 4; ++rr) {
            int row = rbase + i * 16 + q * 4 + rr;
            if (row < n) {
#pragma unroll
                for (int j = 0; j < 8; ++j) {
                    int col = j * 16 + cid;
                    float v = fmaxf(acc[i][j][rr] + bo[j], 0.f);
                    if (OUT_BF16) outbf[(size_t)row * 128 + col] = f32_to_bf16_rne(v);
                    else          outf[(size_t)row * 128 + col] = v;
                }
            }
        }
    }
}

// ---- layer-2 variant: h3 never materialized; epilogue computes d1/d3 -> fin[:,0],fin[:,2]

template <int KH>
__launch_bounds__(256, 2)
__global__ void gemm_mfma_fin(const ushortT* __restrict__ Am, const ushortT* __restrict__ Ah,
                              const ushortT* __restrict__ Wt, const float* __restrict__ bias,
                              const float* __restrict__ Wfc, const float* __restrict__ bfc,
                              float* __restrict__ fin, int n) {
    constexpr int KT = 2 * KH;
    __shared__ ushortT sW[128 * KT];
    int t = threadIdx.x;
    constexpr int TOT16 = 128 * KT * 2 / 16;
    {
        const uint4* Wg = (const uint4*)Wt;
        uint4* Ws = (uint4*)sW;
        for (int j = t; j < TOT16; j += 256) Ws[j] = Wg[j];
    }
    __syncthreads();
    int wv = t >> 6, lane = t & 63;
    int q = lane >> 4, cid = lane & 15;
    int rbase = blockIdx.x * 128 + wv * 32;
    int r0 = rbase + cid, r1 = r0 + 16;
    int r0c = min(r0, n - 1), r1c = min(r1, n - 1);
    float4v acc[2][8];
#pragma unroll
    for (int i = 0; i < 2; i++)
#pragma unroll
        for (int j = 0; j < 8; j++) acc[i][j] = (float4v){0.f, 0.f, 0.f, 0.f};
    int swz = q * 8 + 8 * cid;
#pragma unroll
    for (int ks = 0; ks < KT / 32; ++ks) {
        int kk = ks * 32;
        const ushortT* abase = (kk < KH) ? Am : Ah;
        int kc = (kk < KH) ? kk : kk - KH;
        short8 a0 = *(const short8*)(abase + (size_t)r0c * KH + kc + q * 8);
        short8 a1 = *(const short8*)(abase + (size_t)r1c * KH + kc + q * 8);
#pragma unroll
        for (int j = 0; j < 8; ++j) {
            int col = j * 16 + cid;
            int p = (kk + swz + j * 128) & (KT - 1);
            short8 b = *(const short8*)(sW + col * KT + p);
            acc[0][j] = __builtin_amdgcn_mfma_f32_16x16x32_bf16(a0, b, acc[0][j], 0, 0, 0);
            acc[1][j] = __builtin_amdgcn_mfma_f32_16x16x32_bf16(a1, b, acc[1][j], 0, 0, 0);
        }
    }
    float bo[8], w1[8], w3[8];
#pragma unroll
    for (int j = 0; j < 8; ++j) {
        int col = j * 16 + cid;
        bo[j] = bias[col];
        w1[j] = Wfc[col * 3 + 0];
        w3[j] = Wfc[col * 3 + 2];
    }
    float bfc0 = bfc[0], bfc2 = bfc[2];
#pragma unroll
    for (int i = 0; i < 2; ++i) {
#pragma unroll
        for (int rr = 0; rr < 4; ++rr) {
            float p1 = 0.f, p3 = 0.f;
#pragma unroll
            for (int j = 0; j < 8; ++j) {
                float v = fmaxf(acc[i][j][rr] + bo[j], 0.f);
                p1 += v * w1[j];
                p3 += v * w3[j];
            }
            p1 += __shfl_xor(p1, 1, 64); p3 += __shfl_xor(p3, 1, 64);
            p1 += __shfl_xor(p1, 2, 64); p3 += __shfl_xor(p3, 2, 64);
            p1 += __shfl_xor(p1, 4, 64); p3 += __shfl_xor(p3, 4, 64);
            p1 += __shfl_xor(p1, 8, 64); p3 += __shfl_xor(p3, 8, 64);
            int row = rbase + i * 16 + q * 4 + rr;
            if (cid == 0 && row < n) {
                fin[(size_t)row * 3 + 0] = p1 + bfc0;
                fin[(size_t)row * 3 + 2] = p3 + bfc2;
            }
        }
    }
}

// ---------------- head: a1 built in registers + a2 MFMA + Wao reduce -> fin[:,1] -------
// A-fragment a1[row][k] = relu(d1[row]*Wa1[0][k] + d3[row]*Wa1[1][k] + ba1[k]) computed
// on the fly; only Wa2 (32 KB) + d1/d3/Wa1/ba1 (~2.5 KB) staged in LDS.

__launch_bounds__(256, 4)
__global__ void head_mfma(const ushortT* __restrict__ Wa2t, const float* __restrict__ Wa1,
                          const float* __restrict__ ba1, const float* __restrict__ ba2,
                          const float* __restrict__ Wao, const float* __restrict__ bao,
                          float* __restrict__ fin, int n) {
    __shared__ ushortT sW[128 * 128];   // 32 KB
    __shared__ float sD1[128], sD3[128];
    __shared__ float sWa1a[128], sWa1b[128], sBa1[128];
    int t = threadIdx.x;
    {
        const uint4* Wg = (const uint4*)Wa2t;
        uint4* Ws = (uint4*)sW;
        for (int j = t; j < 2048; j += 256) Ws[j] = Wg[j];
    }
    int rbase = blockIdx.x * 128;
    if (t < 128) {
        sWa1a[t] = Wa1[t];
        sWa1b[t] = Wa1[128 + t];
        sBa1[t] = ba1[t];
        int row = min(rbase + t, n - 1);
        sD1[t] = fin[(size_t)row * 3 + 0];
        sD3[t] = fin[(size_t)row * 3 + 2];
    }
    __syncthreads();
    int wv = t >> 6, lane = t & 63;
    int q = lane >> 4, cid = lane & 15;
    int rl0 = wv * 32 + cid, rl1 = rl0 + 16;
    float d1a = sD1[rl0], d3a = sD3[rl0];
    float d1b = sD1[rl1], d3b = sD3[rl1];
    float4v acc[2][8];
#pragma unroll
    for (int i = 0; i < 2; i++)
#pragma unroll
        for (int j = 0; j < 8; j++) acc[i][j] = (float4v){0.f, 0.f, 0.f, 0.f};
    int swz = q * 8 + 8 * cid;
#pragma unroll
    for (int ks = 0; ks < 4; ++ks) {
        int k0 = ks * 32 + q * 8;
        short8 a0, a1;
#pragma unroll
        for (int j = 0; j < 8; ++j) {
            int k = k0 + j;
            float w0 = sWa1a[k], w1 = sWa1b[k], bb = sBa1[k];
            float v0 = fmaxf(fmaf(d1a, w0, fmaf(d3a, w1, bb)), 0.f);
            float v1 = fmaxf(fmaf(d1b, w0, fmaf(d3b, w1, bb)), 0.f);
            a0[j] = (short)f32_to_bf16_rne(v0);
            a1[j] = (short)f32_to_bf16_rne(v1);
        }
        int p = (ks * 32 + swz) & 127;
#pragma unroll
        for (int j = 0; j < 8; ++j) {
            short8 b = *(const short8*)(sW + (j * 16 + cid) * 128 + p);
            acc[0][j] = __builtin_amdgcn_mfma_f32_16x16x32_bf16(a0, b, acc[0][j], 0, 0, 0);
            acc[1][j] = __builtin_amdgcn_mfma_f32_16x16x32_bf16(a1, b, acc[1][j], 0, 0, 0);
        }
    }
    float b2[8], wo[8];
#pragma unroll
    for (int j = 0; j < 8; ++j) {
        int col = j * 16 + cid;
        b2[j] = ba2[col];
        wo[j] = Wao[col];
    }
    float bao0 = bao[0];
#pragma unroll
    for (int i = 0; i < 2; ++i) {
#pragma unroll
        for (int rr = 0; rr < 4; ++rr) {
            float s = 0.f;
#pragma unroll
            for (int j = 0; j < 8; ++j) s += fmaxf(acc[i][j][rr] + b2[j], 0.f) * wo[j];
            s += __shfl_xor(s, 1, 64);
            s += __shfl_xor(s, 2, 64);
            s += __shfl_xor(s, 4, 64);
            s += __shfl_xor(s, 8, 64);
            int row = rbase + wv * 32 + i * 16 + q * 4 + rr;
            if (cid == 0 && row < n) fin[(size_t)row * 3 + 1] = s + bao0;
        }
    }
}

// ---------------- per-graph mean pool ----------------

__global__ void pool_kernel(const float* __restrict__ fin, const int* __restrict__ batch,
                            float* __restrict__ out, int n) {
    int g = blockIdx.x, t = threadIdx.x;
    int lo = 0, hi = n;
    while (lo < hi) { int mid = (lo + hi) >> 1; if (batch[mid] < g) lo = mid + 1; else hi = mid; }
    int start = lo;
    lo = 0; hi = n;
    while (lo < hi) { int mid = (lo + hi) >> 1; if (batch[mid] < g + 1) lo = mid + 1; else hi = mid; }
    int end = lo;
    float s0 = 0.f, s1 = 0.f, s2 = 0.f;
    for (int i = start + t; i < end; i += 256) {
        s0 += fin[(size_t)i * 3 + 0];
        s1 += fin[(size_t)i * 3 + 1];
        s2 += fin[(size_t)i * 3 + 2];
    }
    __shared__ float r0[256], r1[256], r2[256];
    r0[t] = s0; r1[t] = s1; r2[t] = s2;
    __syncthreads();
    for (int off = 128; off > 0; off >>= 1) {
        if (t < off) { r0[t] += r0[t + off]; r1[t] += r1[t + off]; r2[t] += r2[t + off]; }
        __syncthreads();
    }
    if (t == 0) {
        float c = (float)max(end - start, 1);
        out[g * 3 + 0] = r0[0] / c;
        out[g * 3 + 1] = r1[0] / c;
        out[g * 3 + 2] = r2[0] / c;
    }
}

// ---------------- launch ----------------

extern "C" void kernel_launch(void* const* d_in, const int* in_sizes, int n_in,
                              void* d_out, int out_size, void* d_ws, size_t ws_size,
                              hipStream_t stream) {
    const float* x    = (const float*)d_in[0];
    const int*   ei   = (const int*)d_in[1];
    const int*   batch= (const int*)d_in[2];
    const float* Wl0  = (const float*)d_in[3];
    const float* bl0  = (const float*)d_in[4];
    const float* Wr0  = (const float*)d_in[5];
    const float* Wl1  = (const float*)d_in[6];
    const float* bl1  = (const float*)d_in[7];
    const float* Wr1  = (const float*)d_in[8];
    const float* Wl2  = (const float*)d_in[9];
    const float* bl2  = (const float*)d_in[10];
    const float* Wr2  = (const float*)d_in[11];
    const float* Wfc  = (const float*)d_in[12];
    const float* bfc  = (const float*)d_in[13];
    const float* Wa1  = (const float*)d_in[14];
    const float* ba1  = (const float*)d_in[15];
    const float* Wa2  = (const float*)d_in[16];
    const float* ba2  = (const float*)d_in[17];
    const float* Wao  = (const float*)d_in[18];
    const float* bao  = (const float*)d_in[19];

    const int N = in_sizes[0] / 32;
    const int E = in_sizes[1] / 2;
    const int G = out_size / 3;
    const int* src = ei;
    const int* dst = ei + E;
    float* out = (float*)d_out;
    const int NB = (N + NR - 1) / NR;

    char* p = (char*)d_ws;
    auto carve = [&](size_t bytes) {
        void* r = (void*)p;
        p += (bytes + 255) & ~(size_t)255;
        return r;
    };
    int*      bcnt     = (int*)carve((size_t)NB * 4);
    int*      bstart   = (int*)carve((size_t)(NB + 1) * 4);
    int*      gcur     = (int*)carve((size_t)NB * 4);
    int*      row_start= (int*)carve((size_t)(N + 1) * 4);
    unsigned* packed   = (unsigned*)carve((size_t)E * 4);
    int*      srcs     = (int*)carve((size_t)E * 4);
    ushortT*  aggbf    = (ushortT*)carve((size_t)N * 128 * 2);
    ushortT*  xbf      = (ushortT*)carve((size_t)N * 32 * 2);
    ushortT*  hbf0     = (ushortT*)carve((size_t)N * 128 * 2);
    ushortT*  hbf1     = (ushortT*)carve((size_t)N * 128 * 2);
    float*    fin      = (float*)carve((size_t)N * 3 * 4);
    ushortT*  Wt0      = (ushortT*)carve((size_t)128 * 64 * 2);
    ushortT*  Wt1      = (ushortT*)carve((size_t)128 * 256 * 2);
    ushortT*  Wt2      = (ushortT*)carve((size_t)128 * 256 * 2);
    ushortT*  Wa2t     = (ushortT*)carve((size_t)128 * 128 * 2);

    const int gemm_grid = (N + 127) / 128;
    const int part_grid = (E + PART_CH - 1) / PART_CH;

    // x -> bf16 ; weight prep
    to_bf16_vec<<<(N * 32 / 4 + 255) / 256, 256, 0, stream>>>(x, xbf, N * 32 / 4);
    prep_wt<<<(128 * 64 + 255) / 256, 256, 0, stream>>>(Wl0, Wr0, Wt0, 32);
    prep_wt<<<(128 * 256 + 255) / 256, 256, 0, stream>>>(Wl1, Wr1, Wt1, 128);
    prep_wt<<<(128 * 256 + 255) / 256, 256, 0, stream>>>(Wl2, Wr2, Wt2, 128);
    prep_w1<<<(128 * 128 + 255) / 256, 256, 0, stream>>>(Wa2, Wa2t);

    // CSR build (bucketed counting sort)
    hipMemsetAsync(bcnt, 0, (size_t)NB * 4, stream);
    bucket_count<<<part_grid, 256, 0, stream>>>(dst, bcnt, E, NB);
    bucket_scan<<<1, 256, 0, stream>>>(bcnt, bstart, gcur, NB, E);
    partition_edges<<<part_grid, 256, 0, stream>>>(src, dst, gcur, packed, E, NB);
    bucket_sort<<<NB, 256, 0, stream>>>(packed, bstart, row_start, srcs, N);

    // layer 0 (KH=32)
    aggregate_mean_bf16<4><<<(N * 2 + 255) / 256, 256, 0, stream>>>(
        (const uint4*)xbf, aggbf, srcs, row_start, N);
    gemm_mfma<32, true><<<gemm_grid, 256, 0, stream>>>(
        aggbf, xbf, Wt0, bl0, (float*)nullptr, hbf0, N);
    // layer 1 (KH=128)
    aggregate_mean_bf16<16><<<(N * 8 + 255) / 256, 256, 0, stream>>>(
        (const uint4*)hbf0, aggbf, srcs, row_start, N);
    gemm_mfma<128, true><<<gemm_grid, 256, 0, stream>>>(
        aggbf, hbf0, Wt1, bl1, (float*)nullptr, hbf1, N);
    // layer 2 (KH=128): fused d1/d3 epilogue -> fin[:,0], fin[:,2]
    aggregate_mean_bf16<16><<<(N * 8 + 255) / 256, 256, 0, stream>>>(
        (const uint4*)hbf1, aggbf, srcs, row_start, N);
    gemm_mfma_fin<128><<<gemm_grid, 256, 0, stream>>>(
        aggbf, hbf1, Wt2, bl2, Wfc, bfc, fin, N);

    // head aux MLP (MFMA, register-built A) -> fin[:,1]
    head_mfma<<<gemm_grid, 256, 0, stream>>>(
        Wa2t, Wa1, ba1, ba2, Wao, bao, fin, N);

    // per-graph mean pool
    pool_kernel<<<G, 256, 0, stream>>>(fin, batch, out, N);
}

// Round 7
// 359.757 us; speedup vs baseline: 3.9250x; 1.1012x over previous
//
#include <hip/hip_runtime.h>

#define NR 128        // dst nodes per bucket
#define PART_CH 4096  // edges per partition/count block
typedef unsigned short ushortT;
typedef __attribute__((ext_vector_type(8))) short short8;
typedef __attribute__((ext_vector_type(4))) float float4v;
typedef __attribute__((ext_vector_type(2))) float float2v;

__device__ __forceinline__ unsigned short f32_to_bf16_rne(float f) {
    unsigned u = __float_as_uint(f);
    unsigned r = (u + 0x7fffu + ((u >> 16) & 1u)) >> 16;
    return (unsigned short)r;
}

__device__ __forceinline__ unsigned char f32_to_fp8(float f) {
    return (unsigned char)(__builtin_amdgcn_cvt_pk_fp8_f32(f, f, 0, false) & 0xff);
}

__device__ __forceinline__ void accum8(float* acc, uint4 v) {
    unsigned u[4] = {v.x, v.y, v.z, v.w};
#pragma unroll
    for (int q = 0; q < 4; q++) {
        acc[2 * q]     += __uint_as_float(u[q] << 16);
        acc[2 * q + 1] += __uint_as_float(u[q] & 0xffff0000u);
    }
}

// 16 fp8 values in a uint4 -> acc[16]
__device__ __forceinline__ void accum16_fp8(float* acc, uint4 v) {
    unsigned u[4] = {v.x, v.y, v.z, v.w};
#pragma unroll
    for (int q = 0; q < 4; q++) {
        float2v lo = __builtin_amdgcn_cvt_pk_f32_fp8(u[q], false);
        float2v hi = __builtin_amdgcn_cvt_pk_f32_fp8(u[q], true);
        acc[4 * q + 0] += lo.x;
        acc[4 * q + 1] += lo.y;
        acc[4 * q + 2] += hi.x;
        acc[4 * q + 3] += hi.y;
    }
}

// ---------------- CSR build: bucketed counting sort ----------------

__launch_bounds__(256)
__global__ void bucket_count(const int* __restrict__ dst, int* __restrict__ bcnt, int E, int NB) {
    __shared__ int h[1024];
    int t = threadIdx.x;
    for (int j = t; j < NB; j += 256) h[j] = 0;
    __syncthreads();
    int e0 = blockIdx.x * PART_CH;
    int e1 = min(e0 + PART_CH, E);
    for (int e = e0 + t; e < e1; e += 256) atomicAdd(&h[dst[e] >> 7], 1);
    __syncthreads();
    for (int j = t; j < NB; j += 256) {
        int v = h[j];
        if (v) atomicAdd(&bcnt[j], v);
    }
}

__launch_bounds__(256)
__global__ void bucket_scan(const int* __restrict__ bcnt, int* __restrict__ bstart,
                            int* __restrict__ gcur, int NB, int E) {
    __shared__ int sh[256];
    int t = threadIdx.x;
    int v[4];
    int tot = 0;
#pragma unroll
    for (int j = 0; j < 4; j++) {
        int idx = t * 4 + j;
        v[j] = (idx < NB) ? bcnt[idx] : 0;
        tot += v[j];
    }
    sh[t] = tot;
    __syncthreads();
    for (int off = 1; off < 256; off <<= 1) {
        int add = (t >= off) ? sh[t - off] : 0;
        __syncthreads();
        sh[t] += add;
        __syncthreads();
    }
    int run = sh[t] - tot;
#pragma unroll
    for (int j = 0; j < 4; j++) {
        int idx = t * 4 + j;
        if (idx < NB) { bstart[idx] = run; gcur[idx] = run; }
        run += v[j];
    }
    if (t == 0) bstart[NB] = E;
}

// partition edges into buckets; packed record = src | (dst&127)<<17  (src < 2^17)
__launch_bounds__(256)
__global__ void partition_edges(const int* __restrict__ src, const int* __restrict__ dst,
                                int* __restrict__ gcur, unsigned* __restrict__ packed,
                                int E, int NB) {
    __shared__ int hist[1024];
    __shared__ int base[1024];
    int t = threadIdx.x;
    int e0 = blockIdx.x * PART_CH;
    int e1 = min(e0 + PART_CH, E);
    for (int j = t; j < NB; j += 256) hist[j] = 0;
    __syncthreads();
    for (int e = e0 + t; e < e1; e += 256) atomicAdd(&hist[dst[e] >> 7], 1);
    __syncthreads();
    for (int j = t; j < NB; j += 256) {
        int h = hist[j];
        base[j] = h ? atomicAdd(&gcur[j], h) : 0;
    }
    __syncthreads();
    for (int j = t; j < NB; j += 256) hist[j] = base[j];
    __syncthreads();
    for (int e = e0 + t; e < e1; e += 256) {
        int d = dst[e];
        int b = d >> 7;
        int pos = atomicAdd(&hist[b], 1);
        packed[pos] = (unsigned)src[e] | ((unsigned)(d & (NR - 1)) << 17);
    }
}

__launch_bounds__(256)
__global__ void bucket_sort(const unsigned* __restrict__ packed, const int* __restrict__ bstart,
                            int* __restrict__ row_start, int* __restrict__ srcs, int N) {
    __shared__ int cnt[NR];
    __shared__ int sc[NR];
    __shared__ int cur[NR];
    int b = blockIdx.x, t = threadIdx.x;
    int nb0 = b * NR;
    int nnode = min(NR, N - nb0);
    int lo = bstart[b], hi = bstart[b + 1];
    if (t < NR) cnt[t] = 0;
    __syncthreads();
    for (int j = lo + t; j < hi; j += 256) atomicAdd(&cnt[packed[j] >> 17], 1);
    __syncthreads();
    if (t < NR) sc[t] = cnt[t];
    __syncthreads();
    for (int off = 1; off < NR; off <<= 1) {
        int add = (t >= off && t < NR) ? sc[t - off] : 0;
        __syncthreads();
        if (t < NR) sc[t] += add;
        __syncthreads();
    }
    if (t < nnode) {
        int s = lo + sc[t] - cnt[t];
        row_start[nb0 + t] = s;
        cur[t] = s;
    }
    if (t == 0 && nb0 + nnode == N) row_start[N] = hi;
    __syncthreads();
    for (int j = lo + t; j < hi; j += 256) {
        unsigned pk = packed[j];
        int pos = atomicAdd(&cur[pk >> 17], 1);
        srcs[pos] = (int)(pk & 0x1FFFFu);
    }
}

// ---------------- f32 -> bf16 ----------------

__global__ void to_bf16_vec(const float* __restrict__ in, ushortT* __restrict__ out, int n4) {
    int t = blockIdx.x * 256 + threadIdx.x;
    if (t < n4) {
        float4 v = ((const float4*)in)[t];
        ushort4 o;
        o.x = f32_to_bf16_rne(v.x);
        o.y = f32_to_bf16_rne(v.y);
        o.z = f32_to_bf16_rne(v.z);
        o.w = f32_to_bf16_rne(v.w);
        ((ushort4*)out)[t] = o;
    }
}

// ---------------- weight prep ----------------

__global__ void prep_wt(const float* __restrict__ Wl, const float* __restrict__ Wr,
                        ushortT* __restrict__ Wt, int KH) {
    int KT = 2 * KH;
    int tid = blockIdx.x * 256 + threadIdx.x;
    if (tid >= 128 * KT) return;
    int col = tid / KT, k = tid - col * KT;
    float v = (k < KH) ? Wl[k * 128 + col] : Wr[(k - KH) * 128 + col];
    int pos = (k + 8 * col) & (KT - 1);
    Wt[col * KT + pos] = f32_to_bf16_rne(v);
}

// single 128x128 weight, same swizzle
__global__ void prep_w1(const float* __restrict__ W, ushortT* __restrict__ Wt) {
    int tid = blockIdx.x * 256 + threadIdx.x;
    if (tid >= 128 * 128) return;
    int col = tid >> 7, k = tid & 127;
    int pos = (k + 8 * col) & 127;
    Wt[col * 128 + pos] = f32_to_bf16_rne(W[k * 128 + col]);
}

// ---------------- aggregation: bf16 input (layer 0, 32 feats) ----------------
// CPN=4 uint4 chunks per row; each thread owns 2 chunks of one node.

template <int CPN>
__launch_bounds__(256)
__global__ void aggregate_mean_bf16(const uint4* __restrict__ hin, ushortT* __restrict__ out,
                                    const int* __restrict__ srcs, const int* __restrict__ rs, int n) {
    constexpr int TPN = CPN / 2;
    int tid = blockIdx.x * 256 + threadIdx.x;
    if (tid >= n * TPN) return;
    int i = tid / TPN;
    int c = tid & (TPN - 1);
    int lo = rs[i], hi = rs[i + 1];
    float acc0[8], acc1[8];
#pragma unroll
    for (int q = 0; q < 8; q++) { acc0[q] = 0.f; acc1[q] = 0.f; }
    int e = lo;
    for (; e + 8 <= hi; e += 8) {
        int s[8];
#pragma unroll
        for (int u = 0; u < 8; u++) s[u] = srcs[e + u];
        uint4 va[8], vb[8];
#pragma unroll
        for (int u = 0; u < 8; u++) {
            va[u] = hin[(size_t)s[u] * CPN + c];
            vb[u] = hin[(size_t)s[u] * CPN + c + TPN];
        }
#pragma unroll
        for (int u = 0; u < 8; u++) { accum8(acc0, va[u]); accum8(acc1, vb[u]); }
    }
    for (; e + 4 <= hi; e += 4) {
        int s[4];
#pragma unroll
        for (int u = 0; u < 4; u++) s[u] = srcs[e + u];
        uint4 va[4], vb[4];
#pragma unroll
        for (int u = 0; u < 4; u++) {
            va[u] = hin[(size_t)s[u] * CPN + c];
            vb[u] = hin[(size_t)s[u] * CPN + c + TPN];
        }
#pragma unroll
        for (int u = 0; u < 4; u++) { accum8(acc0, va[u]); accum8(acc1, vb[u]); }
    }
    for (; e < hi; ++e) {
        int s = srcs[e];
        accum8(acc0, hin[(size_t)s * CPN + c]);
        accum8(acc1, hin[(size_t)s * CPN + c + TPN]);
    }
    float inv = 1.0f / (float)max(hi - lo, 1);
    uint4 o0, o1;
    o0.x = (unsigned)f32_to_bf16_rne(acc0[0] * inv) | ((unsigned)f32_to_bf16_rne(acc0[1] * inv) << 16);
    o0.y = (unsigned)f32_to_bf16_rne(acc0[2] * inv) | ((unsigned)f32_to_bf16_rne(acc0[3] * inv) << 16);
    o0.z = (unsigned)f32_to_bf16_rne(acc0[4] * inv) | ((unsigned)f32_to_bf16_rne(acc0[5] * inv) << 16);
    o0.w = (unsigned)f32_to_bf16_rne(acc0[6] * inv) | ((unsigned)f32_to_bf16_rne(acc0[7] * inv) << 16);
    o1.x = (unsigned)f32_to_bf16_rne(acc1[0] * inv) | ((unsigned)f32_to_bf16_rne(acc1[1] * inv) << 16);
    o1.y = (unsigned)f32_to_bf16_rne(acc1[2] * inv) | ((unsigned)f32_to_bf16_rne(acc1[3] * inv) << 16);
    o1.z = (unsigned)f32_to_bf16_rne(acc1[4] * inv) | ((unsigned)f32_to_bf16_rne(acc1[5] * inv) << 16);
    o1.w = (unsigned)f32_to_bf16_rne(acc1[6] * inv) | ((unsigned)f32_to_bf16_rne(acc1[7] * inv) << 16);
    ((uint4*)out)[(size_t)i * CPN + c] = o0;
    ((uint4*)out)[(size_t)i * CPN + c + TPN] = o1;
}

// ---------------- aggregation: fp8 input (layers 1/2, 128 feats) ----------------
// row = 128 fp8 = 8 uint4; 8 threads/node, 1 uint4 (16 feats) each; f32 acc; bf16 out.

__launch_bounds__(256)
__global__ void aggregate_mean_fp8(const uint4* __restrict__ hin, ushortT* __restrict__ out,
                                   const int* __restrict__ srcs, const int* __restrict__ rs, int n) {
    int tid = blockIdx.x * 256 + threadIdx.x;
    if (tid >= n * 8) return;
    int i = tid >> 3;
    int c = tid & 7;
    int lo = rs[i], hi = rs[i + 1];
    float acc[16];
#pragma unroll
    for (int q = 0; q < 16; q++) acc[q] = 0.f;
    int e = lo;
    for (; e + 8 <= hi; e += 8) {
        int s[8];
#pragma unroll
        for (int u = 0; u < 8; u++) s[u] = srcs[e + u];
        uint4 v[8];
#pragma unroll
        for (int u = 0; u < 8; u++) v[u] = hin[(size_t)s[u] * 8 + c];
#pragma unroll
        for (int u = 0; u < 8; u++) accum16_fp8(acc, v[u]);
    }
    for (; e + 4 <= hi; e += 4) {
        int s[4];
#pragma unroll
        for (int u = 0; u < 4; u++) s[u] = srcs[e + u];
        uint4 v[4];
#pragma unroll
        for (int u = 0; u < 4; u++) v[u] = hin[(size_t)s[u] * 8 + c];
#pragma unroll
        for (int u = 0; u < 4; u++) accum16_fp8(acc, v[u]);
    }
    for (; e < hi; ++e) accum16_fp8(acc, hin[(size_t)srcs[e] * 8 + c]);
    float inv = 1.0f / (float)max(hi - lo, 1);
    uint4 o0, o1;
    o0.x = (unsigned)f32_to_bf16_rne(acc[0] * inv)  | ((unsigned)f32_to_bf16_rne(acc[1] * inv) << 16);
    o0.y = (unsigned)f32_to_bf16_rne(acc[2] * inv)  | ((unsigned)f32_to_bf16_rne(acc[3] * inv) << 16);
    o0.z = (unsigned)f32_to_bf16_rne(acc[4] * inv)  | ((unsigned)f32_to_bf16_rne(acc[5] * inv) << 16);
    o0.w = (unsigned)f32_to_bf16_rne(acc[6] * inv)  | ((unsigned)f32_to_bf16_rne(acc[7] * inv) << 16);
    o1.x = (unsigned)f32_to_bf16_rne(acc[8] * inv)  | ((unsigned)f32_to_bf16_rne(acc[9] * inv) << 16);
    o1.y = (unsigned)f32_to_bf16_rne(acc[10] * inv) | ((unsigned)f32_to_bf16_rne(acc[11] * inv) << 16);
    o1.z = (unsigned)f32_to_bf16_rne(acc[12] * inv) | ((unsigned)f32_to_bf16_rne(acc[13] * inv) << 16);
    o1.w = (unsigned)f32_to_bf16_rne(acc[14] * inv) | ((unsigned)f32_to_bf16_rne(acc[15] * inv) << 16);
    ((uint4*)out)[(size_t)i * 16 + c * 2]     = o0;
    ((uint4*)out)[(size_t)i * 16 + c * 2 + 1] = o1;
}

// ---------------- MFMA GEMM: out = relu([Am | Ah] @ [Wl;Wr] + bias) --------------------
// optional dual write: bf16 (next self-term) + fp8 (next gather payload)

template <int KH, bool OUT_BF16, bool OUT_FP8>
__launch_bounds__(256, 2)
__global__ void gemm_mfma(const ushortT* __restrict__ Am, const ushortT* __restrict__ Ah,
                          const ushortT* __restrict__ Wt, const float* __restrict__ bias,
                          float* __restrict__ outf, ushortT* __restrict__ outbf,
                          unsigned char* __restrict__ outf8, int n) {
    constexpr int KT = 2 * KH;
    __shared__ ushortT sW[128 * KT];
    int t = threadIdx.x;
    constexpr int TOT16 = 128 * KT * 2 / 16;
    {
        const uint4* Wg = (const uint4*)Wt;
        uint4* Ws = (uint4*)sW;
        for (int j = t; j < TOT16; j += 256) Ws[j] = Wg[j];
    }
    __syncthreads();
    int wv = t >> 6, lane = t & 63;
    int q = lane >> 4, cid = lane & 15;
    int rbase = blockIdx.x * 128 + wv * 32;
    int r0 = rbase + cid, r1 = r0 + 16;
    int r0c = min(r0, n - 1), r1c = min(r1, n - 1);
    float4v acc[2][8];
#pragma unroll
    for (int i = 0; i < 2; i++)
#pragma unroll
        for (int j = 0; j < 8; j++) acc[i][j] = (float4v){0.f, 0.f, 0.f, 0.f};
    int swz = q * 8 + 8 * cid;
#pragma unroll
    for (int ks = 0; ks < KT / 32; ++ks) {
        int kk = ks * 32;
        const ushortT* abase = (kk < KH) ? Am : Ah;
        int kc = (kk < KH) ? kk : kk - KH;
        short8 a0 = *(const short8*)(abase + (size_t)r0c * KH + kc + q * 8);
        short8 a1 = *(const short8*)(abase + (size_t)r1c * KH + kc + q * 8);
#pragma unroll
        for (int j = 0; j < 8; ++j) {
            int col = j * 16 + cid;
            int p = (kk + swz + j * 128) & (KT - 1);
            short8 b = *(const short8*)(sW + col * KT + p);
            acc[0][j] = __builtin_amdgcn_mfma_f32_16x16x32_bf16(a0, b, acc[0][j], 0, 0, 0);
            acc[1][j] = __builtin_amdgcn_mfma_f32_16x16x32_bf16(a1, b, acc[1][j], 0, 0, 0);
        }
    }
    float bo[8];
#pragma unroll
    for (int j = 0; j < 8; ++j) bo[j] = bias[j * 16 + cid];
#pragma unroll
    for (int i = 0; i < 2; ++i) {
#pragma unroll
        for (int rr = 0; rr < 4; ++rr) {
            int row = rbase + i * 16 + q * 4 + rr;
            if (row < n) {
#pragma unroll
                for (int j = 0; j < 8; ++j) {
                    int col = j * 16 + cid;
                    float v = fmaxf(acc[i][j][rr] + bo[j], 0.f);
                    if (OUT_BF16) outbf[(size_t)row * 128 + col] = f32_to_bf16_rne(v);
                    if (OUT_FP8)  outf8[(size_t)row * 128 + col] = f32_to_fp8(v);
                    if (!OUT_BF16 && !OUT_FP8) outf[(size_t)row * 128 + col] = v;
                }
            }
        }
    }
}

// ---- layer-2 variant: h3 never materialized; epilogue computes d1/d3 -> fin[:,0],fin[:,2]

template <int KH>
__launch_bounds__(256, 2)
__global__ void gemm_mfma_fin(const ushortT* __restrict__ Am, const ushortT* __restrict__ Ah,
                              const ushortT* __restrict__ Wt, const float* __restrict__ bias,
                              const float* __restrict__ Wfc, const float* __restrict__ bfc,
                              float* __restrict__ fin, int n) {
    constexpr int KT = 2 * KH;
    __shared__ ushortT sW[128 * KT];
    int t = threadIdx.x;
    constexpr int TOT16 = 128 * KT * 2 / 16;
    {
        const uint4* Wg = (const uint4*)Wt;
        uint4* Ws = (uint4*)sW;
        for (int j = t; j < TOT16; j += 256) Ws[j] = Wg[j];
    }
    __syncthreads();
    int wv = t >> 6, lane = t & 63;
    int q = lane >> 4, cid = lane & 15;
    int rbase = blockIdx.x * 128 + wv * 32;
    int r0 = rbase + cid, r1 = r0 + 16;
    int r0c = min(r0, n - 1), r1c = min(r1, n - 1);
    float4v acc[2][8];
#pragma unroll
    for (int i = 0; i < 2; i++)
#pragma unroll
        for (int j = 0; j < 8; j++) acc[i][j] = (float4v){0.f, 0.f, 0.f, 0.f};
    int swz = q * 8 + 8 * cid;
#pragma unroll
    for (int ks = 0; ks < KT / 32; ++ks) {
        int kk = ks * 32;
        const ushortT* abase = (kk < KH) ? Am : Ah;
        int kc = (kk < KH) ? kk : kk - KH;
        short8 a0 = *(const short8*)(abase + (size_t)r0c * KH + kc + q * 8);
        short8 a1 = *(const short8*)(abase + (size_t)r1c * KH + kc + q * 8);
#pragma unroll
        for (int j = 0; j < 8; ++j) {
            int col = j * 16 + cid;
            int p = (kk + swz + j * 128) & (KT - 1);
            short8 b = *(const short8*)(sW + col * KT + p);
            acc[0][j] = __builtin_amdgcn_mfma_f32_16x16x32_bf16(a0, b, acc[0][j], 0, 0, 0);
            acc[1][j] = __builtin_amdgcn_mfma_f32_16x16x32_bf16(a1, b, acc[1][j], 0, 0, 0);
        }
    }
    float bo[8], w1[8], w3[8];
#pragma unroll
    for (int j = 0; j < 8; ++j) {
        int col = j * 16 + cid;
        bo[j] = bias[col];
        w1[j] = Wfc[col * 3 + 0];
        w3[j] = Wfc[col * 3 + 2];
    }
    float bfc0 = bfc[0], bfc2 = bfc[2];
#pragma unroll
    for (int i = 0; i < 2; ++i) {
#pragma unroll
        for (int rr = 0; rr < 4; ++rr) {
            float p1 = 0.f, p3 = 0.f;
#pragma unroll
            for (int j = 0; j < 8; ++j) {
                float v = fmaxf(acc[i][j][rr] + bo[j], 0.f);
                p1 += v * w1[j];
                p3 += v * w3[j];
            }
            p1 += __shfl_xor(p1, 1, 64); p3 += __shfl_xor(p3, 1, 64);
            p1 += __shfl_xor(p1, 2, 64); p3 += __shfl_xor(p3, 2, 64);
            p1 += __shfl_xor(p1, 4, 64); p3 += __shfl_xor(p3, 4, 64);
            p1 += __shfl_xor(p1, 8, 64); p3 += __shfl_xor(p3, 8, 64);
            int row = rbase + i * 16 + q * 4 + rr;
            if (cid == 0 && row < n) {
                fin[(size_t)row * 3 + 0] = p1 + bfc0;
                fin[(size_t)row * 3 + 2] = p3 + bfc2;
            }
        }
    }
}

// ---------------- head: a1 built in registers + a2 MFMA + Wao reduce -> fin[:,1] -------

__launch_bounds__(256, 4)
__global__ void head_mfma(const ushortT* __restrict__ Wa2t, const float* __restrict__ Wa1,
                          const float* __restrict__ ba1, const float* __restrict__ ba2,
                          const float* __restrict__ Wao, const float* __restrict__ bao,
                          float* __restrict__ fin, int n) {
    __shared__ ushortT sW[128 * 128];   // 32 KB
    __shared__ float sD1[128], sD3[128];
    __shared__ float sWa1a[128], sWa1b[128], sBa1[128];
    int t = threadIdx.x;
    {
        const uint4* Wg = (const uint4*)Wa2t;
        uint4* Ws = (uint4*)sW;
        for (int j = t; j < 2048; j += 256) Ws[j] = Wg[j];
    }
    int rbase = blockIdx.x * 128;
    if (t < 128) {
        sWa1a[t] = Wa1[t];
        sWa1b[t] = Wa1[128 + t];
        sBa1[t] = ba1[t];
        int row = min(rbase + t, n - 1);
        sD1[t] = fin[(size_t)row * 3 + 0];
        sD3[t] = fin[(size_t)row * 3 + 2];
    }
    __syncthreads();
    int wv = t >> 6, lane = t & 63;
    int q = lane >> 4, cid = lane & 15;
    int rl0 = wv * 32 + cid, rl1 = rl0 + 16;
    float d1a = sD1[rl0], d3a = sD3[rl0];
    float d1b = sD1[rl1], d3b = sD3[rl1];
    float4v acc[2][8];
#pragma unroll
    for (int i = 0; i < 2; i++)
#pragma unroll
        for (int j = 0; j < 8; j++) acc[i][j] = (float4v){0.f, 0.f, 0.f, 0.f};
    int swz = q * 8 + 8 * cid;
#pragma unroll
    for (int ks = 0; ks < 4; ++ks) {
        int k0 = ks * 32 + q * 8;
        short8 a0, a1;
#pragma unroll
        for (int j = 0; j < 8; ++j) {
            int k = k0 + j;
            float w0 = sWa1a[k], w1 = sWa1b[k], bb = sBa1[k];
            float v0 = fmaxf(fmaf(d1a, w0, fmaf(d3a, w1, bb)), 0.f);
            float v1 = fmaxf(fmaf(d1b, w0, fmaf(d3b, w1, bb)), 0.f);
            a0[j] = (short)f32_to_bf16_rne(v0);
            a1[j] = (short)f32_to_bf16_rne(v1);
        }
        int p = (ks * 32 + swz) & 127;
#pragma unroll
        for (int j = 0; j < 8; ++j) {
            short8 b = *(const short8*)(sW + (j * 16 + cid) * 128 + p);
            acc[0][j] = __builtin_amdgcn_mfma_f32_16x16x32_bf16(a0, b, acc[0][j], 0, 0, 0);
            acc[1][j] = __builtin_amdgcn_mfma_f32_16x16x32_bf16(a1, b, acc[1][j], 0, 0, 0);
        }
    }
    float b2[8], wo[8];
#pragma unroll
    for (int j = 0; j < 8; ++j) {
        int col = j * 16 + cid;
        b2[j] = ba2[col];
        wo[j] = Wao[col];
    }
    float bao0 = bao[0];
#pragma unroll
    for (int i = 0; i < 2; ++i) {
#pragma unroll
        for (int rr = 0; rr < 4; ++rr) {
            float s = 0.f;
#pragma unroll
            for (int j = 0; j < 8; ++j) s += fmaxf(acc[i][j][rr] + b2[j], 0.f) * wo[j];
            s += __shfl_xor(s, 1, 64);
            s += __shfl_xor(s, 2, 64);
            s += __shfl_xor(s, 4, 64);
            s += __shfl_xor(s, 8, 64);
            int row = rbase + wv * 32 + i * 16 + q * 4 + rr;
            if (cid == 0 && row < n) fin[(size_t)row * 3 + 1] = s + bao0;
        }
    }
}

// ---------------- per-graph mean pool ----------------

__global__ void pool_kernel(const float* __restrict__ fin, const int* __restrict__ batch,
                            float* __restrict__ out, int n) {
    int g = blockIdx.x, t = threadIdx.x;
    int lo = 0, hi = n;
    while (lo < hi) { int mid = (lo + hi) >> 1; if (batch[mid] < g) lo = mid + 1; else hi = mid; }
    int start = lo;
    lo = 0; hi = n;
    while (lo < hi) { int mid = (lo + hi) >> 1; if (batch[mid] < g + 1) lo = mid + 1; else hi = mid; }
    int end = lo;
    float s0 = 0.f, s1 = 0.f, s2 = 0.f;
    for (int i = start + t; i < end; i += 256) {
        s0 += fin[(size_t)i * 3 + 0];
        s1 += fin[(size_t)i * 3 + 1];
        s2 += fin[(size_t)i * 3 + 2];
    }
    __shared__ float r0[256], r1[256], r2[256];
    r0[t] = s0; r1[t] = s1; r2[t] = s2;
    __syncthreads();
    for (int off = 128; off > 0; off >>= 1) {
        if (t < off) { r0[t] += r0[t + off]; r1[t] += r1[t + off]; r2[t] += r2[t + off]; }
        __syncthreads();
    }
    if (t == 0) {
        float c = (float)max(end - start, 1);
        out[g * 3 + 0] = r0[0] / c;
        out[g * 3 + 1] = r1[0] / c;
        out[g * 3 + 2] = r2[0] / c;
    }
}

// ---------------- launch ----------------

extern "C" void kernel_launch(void* const* d_in, const int* in_sizes, int n_in,
                              void* d_out, int out_size, void* d_ws, size_t ws_size,
                              hipStream_t stream) {
    const float* x    = (const float*)d_in[0];
    const int*   ei   = (const int*)d_in[1];
    const int*   batch= (const int*)d_in[2];
    const float* Wl0  = (const float*)d_in[3];
    const float* bl0  = (const float*)d_in[4];
    const float* Wr0  = (const float*)d_in[5];
    const float* Wl1  = (const float*)d_in[6];
    const float* bl1  = (const float*)d_in[7];
    const float* Wr1  = (const float*)d_in[8];
    const float* Wl2  = (const float*)d_in[9];
    const float* bl2  = (const float*)d_in[10];
    const float* Wr2  = (const float*)d_in[11];
    const float* Wfc  = (const float*)d_in[12];
    const float* bfc  = (const float*)d_in[13];
    const float* Wa1  = (const float*)d_in[14];
    const float* ba1  = (const float*)d_in[15];
    const float* Wa2  = (const float*)d_in[16];
    const float* ba2  = (const float*)d_in[17];
    const float* Wao  = (const float*)d_in[18];
    const float* bao  = (const float*)d_in[19];

    const int N = in_sizes[0] / 32;
    const int E = in_sizes[1] / 2;
    const int G = out_size / 3;
    const int* src = ei;
    const int* dst = ei + E;
    float* out = (float*)d_out;
    const int NB = (N + NR - 1) / NR;

    char* p = (char*)d_ws;
    auto carve = [&](size_t bytes) {
        void* r = (void*)p;
        p += (bytes + 255) & ~(size_t)255;
        return r;
    };
    int*           bcnt     = (int*)carve((size_t)NB * 4);
    int*           bstart   = (int*)carve((size_t)(NB + 1) * 4);
    int*           gcur     = (int*)carve((size_t)NB * 4);
    int*           row_start= (int*)carve((size_t)(N + 1) * 4);
    unsigned*      packed   = (unsigned*)carve((size_t)E * 4);
    int*           srcs     = (int*)carve((size_t)E * 4);
    ushortT*       aggbf    = (ushortT*)carve((size_t)N * 128 * 2);
    ushortT*       xbf      = (ushortT*)carve((size_t)N * 32 * 2);
    ushortT*       hbf0     = (ushortT*)carve((size_t)N * 128 * 2);
    ushortT*       hbf1     = (ushortT*)carve((size_t)N * 128 * 2);
    unsigned char* hf8_0    = (unsigned char*)carve((size_t)N * 128);
    unsigned char* hf8_1    = (unsigned char*)carve((size_t)N * 128);
    float*         fin      = (float*)carve((size_t)N * 3 * 4);
    ushortT*       Wt0      = (ushortT*)carve((size_t)128 * 64 * 2);
    ushortT*       Wt1      = (ushortT*)carve((size_t)128 * 256 * 2);
    ushortT*       Wt2      = (ushortT*)carve((size_t)128 * 256 * 2);
    ushortT*       Wa2t     = (ushortT*)carve((size_t)128 * 128 * 2);

    const int gemm_grid = (N + 127) / 128;
    const int part_grid = (E + PART_CH - 1) / PART_CH;

    // x -> bf16 ; weight prep
    to_bf16_vec<<<(N * 32 / 4 + 255) / 256, 256, 0, stream>>>(x, xbf, N * 32 / 4);
    prep_wt<<<(128 * 64 + 255) / 256, 256, 0, stream>>>(Wl0, Wr0, Wt0, 32);
    prep_wt<<<(128 * 256 + 255) / 256, 256, 0, stream>>>(Wl1, Wr1, Wt1, 128);
    prep_wt<<<(128 * 256 + 255) / 256, 256, 0, stream>>>(Wl2, Wr2, Wt2, 128);
    prep_w1<<<(128 * 128 + 255) / 256, 256, 0, stream>>>(Wa2, Wa2t);

    // CSR build (bucketed counting sort)
    hipMemsetAsync(bcnt, 0, (size_t)NB * 4, stream);
    bucket_count<<<part_grid, 256, 0, stream>>>(dst, bcnt, E, NB);
    bucket_scan<<<1, 256, 0, stream>>>(bcnt, bstart, gcur, NB, E);
    partition_edges<<<part_grid, 256, 0, stream>>>(src, dst, gcur, packed, E, NB);
    bucket_sort<<<NB, 256, 0, stream>>>(packed, bstart, row_start, srcs, N);

    // layer 0 (KH=32): bf16 gather on x; dual-write h0 (bf16 + fp8)
    aggregate_mean_bf16<4><<<(N * 2 + 255) / 256, 256, 0, stream>>>(
        (const uint4*)xbf, aggbf, srcs, row_start, N);
    gemm_mfma<32, true, true><<<gemm_grid, 256, 0, stream>>>(
        aggbf, xbf, Wt0, bl0, (float*)nullptr, hbf0, hf8_0, N);
    // layer 1 (KH=128): fp8 gather on h0; dual-write h1
    aggregate_mean_fp8<<<(N * 8 + 255) / 256, 256, 0, stream>>>(
        (const uint4*)hf8_0, aggbf, srcs, row_start, N);
    gemm_mfma<128, true, true><<<gemm_grid, 256, 0, stream>>>(
        aggbf, hbf0, Wt1, bl1, (float*)nullptr, hbf1, hf8_1, N);
    // layer 2 (KH=128): fp8 gather on h1; fused d1/d3 epilogue -> fin
    aggregate_mean_fp8<<<(N * 8 + 255) / 256, 256, 0, stream>>>(
        (const uint4*)hf8_1, aggbf, srcs, row_start, N);
    gemm_mfma_fin<128><<<gemm_grid, 256, 0, stream>>>(
        aggbf, hbf1, Wt2, bl2, Wfc, bfc, fin, N);

    // head aux MLP (MFMA, register-built A) -> fin[:,1]
    head_mfma<<<gemm_grid, 256, 0, stream>>>(
        Wa2t, Wa1, ba1, ba2, Wao, bao, fin, N);

    // per-graph mean pool
    pool_kernel<<<G, 256, 0, stream>>>(fin, batch, out, N);
}